// Round 23
// baseline (118.611 us; speedup 1.0000x reference)
//
#include <hip/hip_runtime.h>
#include <math.h>

#define H 1024
#define W 1024
#define B 8
#define TOPK 4096
#define CAP 131072
#define NBT 4096
#define NCH 8
#define GK 20480
#define TILE_X 108
#define TILE_Y 108
#define GDX 10
#define GDY 10
#define SKCAP 2048

typedef unsigned long long u64;
typedef unsigned int u32;
typedef unsigned short u16;

// DPP lane shifts (VALU, no DS). wave_shr1 (0x138) == shfl_up(v,1);
// wave_shl1 (0x130) == shfl_down(v,1). bound_ctrl zero-fill at lanes 0/63 is
// harmless: those lanes own region cols {0,1}/{126,127}, excluded by extents.
__device__ __forceinline__ float dpp_up1(float v) {
    int r = __builtin_amdgcn_update_dpp(0, __float_as_int(v), 0x138, 0xF, 0xF, true);
    return __int_as_float(r);
}
__device__ __forceinline__ float dpp_dn1(float v) {
    int r = __builtin_amdgcn_update_dpp(0, __float_as_int(v), 0x130, 0xF, 0xF, true);
    return __int_as_float(r);
}

// Monotone bin index, fine-grained where survivor values cluster (v in [0.5,1)).
// exp==0x7E: bins 64..4095 via mantissa[22:11] (~128 keys/bin near threshold).
__device__ __forceinline__ int binOf(u64 key) {
    u32 fb = (u32)(key >> 32);
    u32 ex = fb >> 23;
    if (ex >= 0x7Fu) return NBT - 1;
    if (ex == 0x7Eu) {
        u32 m12 = (fb >> 11) & 0xFFFu;
        return (m12 < 64u) ? 64 : (int)m12;
    }
    if (ex >= 0x6Eu) return (int)(ex - 0x6Eu + 47u);
    return 1;
}

// ================= Fused 3-round NMS + survivor compaction (round-21 verbatim) =================
#define ROUND_A(VR0, VR1, USE_SUPP)                                               \
    _Pragma("unroll") for (int i = 0; i < 16; ++i) {                              \
        int r = rbase + i;                                                        \
        if (r < (VR0) || r > (VR1)) continue;                                     \
        float x = svx[i], y = svy[i];                                             \
        if (USE_SUPP) {                                                           \
            u64 se = sp[r][0], so = sp[r][1];                                     \
            u32 s0 = (u32)(se >> lane) & 1u;                                      \
            u32 s1 = (u32)(so >> lane) & 1u;                                      \
            sbx |= s0 << i;                                                       \
            sby |= s1 << i;                                                       \
            if (s0) x = 0.0f;                                                     \
            if (s1) y = 0.0f;                                                     \
        }                                                                         \
        float ux = dpp_up1(x), uy = dpp_up1(y);                                   \
        float dxx = dpp_dn1(x), dyy = dpp_dn1(y);                                 \
        float m01 = fmaxf(x, y);                                                  \
        float h0 = fmaxf(fmaxf(ux, uy), fmaxf(m01, dxx));                         \
        float h1 = fmaxf(fmaxf(uy, m01), fmaxf(dxx, dyy));                        \
        h0r[i] = h0;                                                              \
        h1r[i] = h1;                                                              \
        if (i == 0 || i == 1 || i == 14 || i == 15) {                             \
            int k = (i < 2) ? i : i - 12;                                         \
            *(float2*)&hb[w * 4 + k][2 * lane] = make_float2(h0, h1);             \
        }                                                                         \
    }

#define ROUND_B(VV0, VV1, USE_SUPP, FIRST)                                        \
    _Pragma("unroll") for (int i = 0; i < 16; ++i) {                              \
        int r = rbase + i;                                                        \
        if (r < (VV0) || r > (VV1)) continue;                                     \
        float v0x, v0y, v1x, v1y, v3x, v3y, v4x, v4y;                             \
        if (i >= 2) { v0x = h0r[i - 2]; v0y = h1r[i - 2]; }                       \
        else { int k = (i == 0) ? 2 : 3;                                          \
               float2 t = *(const float2*)&hb[(w - 1) * 4 + k][2 * lane];         \
               v0x = t.x; v0y = t.y; }                                            \
        if (i >= 1) { v1x = h0r[i - 1]; v1y = h1r[i - 1]; }                       \
        else { float2 t = *(const float2*)&hb[(w - 1) * 4 + 3][2 * lane];         \
               v1x = t.x; v1y = t.y; }                                            \
        if (i <= 14) { v3x = h0r[i + 1]; v3y = h1r[i + 1]; }                      \
        else { float2 t = *(const float2*)&hb[(w + 1) * 4 + 0][2 * lane];         \
               v3x = t.x; v3y = t.y; }                                            \
        if (i <= 13) { v4x = h0r[i + 2]; v4y = h1r[i + 2]; }                      \
        else { int k = (i == 14) ? 0 : 1;                                         \
               float2 t = *(const float2*)&hb[(w + 1) * 4 + k][2 * lane];         \
               v4x = t.x; v4y = t.y; }                                            \
        float vm0 = fmaxf(fmaxf(fmaxf(v0x, v1x), fmaxf(v3x, v4x)), h0r[i]);       \
        float vm1 = fmaxf(fmaxf(fmaxf(v0y, v1y), fmaxf(v3y, v4y)), h1r[i]);       \
        float x = svx[i], y = svy[i];                                             \
        bool sb0 = false, sb1 = false;                                            \
        if (USE_SUPP) {                                                           \
            sb0 = (sbx >> i) & 1u;                                                \
            sb1 = (sby >> i) & 1u;                                                \
            if (sb0) x = 0.0f;                                                    \
            if (sb1) y = 0.0f;                                                    \
        }                                                                         \
        int c0 = 2 * lane;                                                        \
        bool bit0 = (x == vm0) && !sb0 && (svx[i] != -INFINITY) &&                \
                    c0 >= (VV0) && c0 <= (VV1);                                   \
        bool bit1 = (y == vm1) && !sb1 && (svy[i] != -INFINITY) &&                \
                    (c0 + 1) >= (VV0) && (c0 + 1) <= (VV1);                       \
        u64 bE = __ballot(bit0), bO = __ballot(bit1);                             \
        if (lane == 0) {                                                          \
            u64 ne = ((FIRST) ? 0ull : ma[r][0]) | bE;                            \
            u64 no = ((FIRST) ? 0ull : ma[r][1]) | bO;                            \
            ma[r][0] = ne;                                                        \
            ma[r][1] = no;                                                        \
        }                                                                         \
    }

#define DILATE(R0, R1)                                                            \
    if (tid >= (R0) && tid <= (R1)) {                                             \
        int rr = tid;                                                             \
        u64 e = ma[rr - 2][0] | ma[rr - 1][0] | ma[rr][0] | ma[rr + 1][0] |       \
                ma[rr + 2][0];                                                    \
        u64 o = ma[rr - 2][1] | ma[rr - 1][1] | ma[rr][1] | ma[rr + 1][1] |       \
                ma[rr + 2][1];                                                    \
        sp[rr][0] = e | (e << 1) | (e >> 1) | o | (o << 1);                       \
        sp[rr][1] = o | (o << 1) | (o >> 1) | e | (e >> 1);                       \
    }

__global__ __launch_bounds__(512) void k_nms(const float* __restrict__ scores,
                                             u64* __restrict__ surv,
                                             u32* __restrict__ cnt) {
    __shared__ float hb[32][128];                  // 16 KB; reused as skeys
    __shared__ __align__(16) u64 ma[128][2];       // [E,O] interleaved
    __shared__ __align__(16) u64 sp[128][2];
    __shared__ u32 lcnt, gbase;
    u64* skeys = (u64*)&hb[0][0];
    const int b = blockIdx.z;
    const int gx0 = blockIdx.x * TILE_X - 10;
    const int gy0 = blockIdx.y * TILE_Y - 10;
    const float* img = scores + (size_t)b * H * W;
    const int tid = (int)threadIdx.x, lane = tid & 63, w = tid >> 6, rbase = w * 16;
    const int gx = gx0 + 2 * lane;
    if (tid == 0) lcnt = 0;

    float svx[16], svy[16], h0r[16], h1r[16];
    u32 sbx = 0, sby = 0;
#pragma unroll
    for (int i = 0; i < 16; ++i) {
        int gy = gy0 + rbase + i;
        float x = -INFINITY, y = -INFINITY;
        if (gy >= 0 && gy < H) {
            const float* row = img + (size_t)gy * W;
            if (gx >= 0 && gx + 1 < W) {
                float2 t = *(const float2*)(row + gx);
                x = t.x; y = t.y;
            } else if (gx >= 0 && gx < W) {
                x = row[gx];
            }
        }
        svx[i] = x; svy[i] = y;
    }

    ROUND_A(0, 127, false)
    __syncthreads();
    ROUND_B(2, 125, false, 1)
    __syncthreads();
    DILATE(4, 123)
    __syncthreads();
    sbx = 0; sby = 0;
    ROUND_A(4, 123, true)
    __syncthreads();
    ROUND_B(6, 121, true, 0)
    __syncthreads();
    DILATE(8, 119)
    __syncthreads();
    sbx = 0; sby = 0;
    ROUND_A(8, 119, true)
    __syncthreads();
    ROUND_B(10, 117, true, 0)
    __syncthreads();   // hb dead -> skeys

#pragma unroll
    for (int i = 0; i < 16; ++i) {
        int r = rbase + i;
        if (r < 10 || r > 117) continue;
        int gy = gy0 + r;
        u64 me = ma[r][0], mo = ma[r][1];
        int c0 = 2 * lane;
        if (c0 >= 10 && c0 <= 117 && ((me >> lane) & 1ull) && svx[i] > 0.0f &&
            gx >= 2 && gx < W - 2 && gy >= 2 && gy < H - 2) {
            u32 pos = atomicAdd(&lcnt, 1u);
            if (pos < SKCAP) {
                u32 p = (u32)(gy * W + gx);
                skeys[pos] = ((u64)__float_as_uint(svx[i]) << 32) | (u64)(~p);
            }
        }
        if (c0 + 1 >= 10 && c0 + 1 <= 117 && ((mo >> lane) & 1ull) && svy[i] > 0.0f &&
            gx + 1 >= 2 && gx + 1 < W - 2 && gy >= 2 && gy < H - 2) {
            u32 pos = atomicAdd(&lcnt, 1u);
            if (pos < SKCAP) {
                u32 p = (u32)(gy * W + gx + 1);
                skeys[pos] = ((u64)__float_as_uint(svy[i]) << 32) | (u64)(~p);
            }
        }
    }
    __syncthreads();
    u32 nk = lcnt < SKCAP ? lcnt : SKCAP;
    if (tid == 0) gbase = nk ? atomicAdd(&cnt[b], nk) : 0u;
    __syncthreads();
    for (u32 i = tid; i < nk; i += 512)
        surv[(size_t)b * CAP + gbase + i] = skeys[i];
}

// ===== per-chunk private histograms; M (u16) layout [img][chunk][bin] =====
__global__ __launch_bounds__(512) void k_hist(const u64* __restrict__ surv,
                                              const u32* __restrict__ cnt,
                                              u16* __restrict__ M) {
    __shared__ u32 h[NBT];
    int img = blockIdx.x / NCH, c = blockIdx.x % NCH;
    int tid = (int)threadIdx.x;
    for (int i = tid; i < NBT; i += 512) h[i] = 0;
    __syncthreads();
    u32 n = cnt[img];
    if (n > CAP) n = CAP;
    u32 chunk = (n + NCH - 1) / NCH;
    u32 lo = c * chunk, hi = min(n, lo + chunk);
    const u64* sv = surv + (size_t)img * CAP;
    for (u32 i = lo + tid; i < hi; i += 512) atomicAdd(&h[binOf(sv[i])], 1u);
    __syncthreads();
    u16* dst = M + ((size_t)img * NCH + c) * NBT;
    for (int i = tid; i < NBT; i += 512) dst[i] = (u16)h[i];
}

// ===== scan: register accumulate (one ushort4/chunk) + shuffle scan =====
__global__ __launch_bounds__(1024) void k_scan(const u16* __restrict__ M,
                                               u32* __restrict__ offC,
                                               u32* __restrict__ basetot,
                                               int* __restrict__ tinfo,
                                               u64* __restrict__ gkeys) {
    __shared__ u32 wsum[16];
    __shared__ u32 sh_ntot;
    __shared__ int sh_T;
    __shared__ u32 sh_r, sh_m;
    int img = blockIdx.x, tid = (int)threadIdx.x;
    const u16* Mi = M + (size_t)img * NCH * NBT;
    const int base = NBT - 4 - tid * 4;  // thread's 4 contiguous bins (tid 0 = top)
    u32 reg[4] = {0, 0, 0, 0};
    for (int c = 0; c < NCH; ++c) {
        const u16* p = Mi + (size_t)c * NBT + base;
        ushort4 a = *(const ushort4*)(p);
        reg[0] += a.x; reg[1] += a.y; reg[2] += a.z; reg[3] += a.w;
    }
    u32 tot = reg[0] + reg[1] + reg[2] + reg[3];
    u32 x = tot;
    int ln = tid & 63, wv = tid >> 6;
#pragma unroll
    for (int off = 1; off < 64; off <<= 1) {
        u32 v = (u32)__shfl_up((int)x, off);
        if (ln >= off) x += v;
    }
    if (ln == 63) wsum[wv] = x;
    __syncthreads();
    if (tid < 16) {
        u32 wval = wsum[tid];
        u32 wx = wval;
        for (int off = 1; off < 16; off <<= 1) {
            u32 v = (u32)__shfl_up((int)wx, off);
            if (tid >= off) wx += v;
        }
        wsum[tid] = wx - wval;
        if (tid == 15) sh_ntot = wx;
    }
    __syncthreads();
    u32 incl = x + wsum[wv];
    u32 excl = incl - tot;
    u32 ntot = sh_ntot;
    if (ntot > TOPK) {
        if (excl < TOPK && TOPK <= incl) {
            u32 cum = excl;
#pragma unroll
            for (int j = 0; j < 4; ++j) {
                u32 cj = reg[3 - j];
                if (cum + cj >= TOPK) {
                    sh_T = NBT - 1 - tid * 4 - j;
                    sh_r = TOPK - cum;
                    sh_m = cj;
                    break;
                }
                cum += cj;
            }
        }
    } else if (tid == 0) { sh_T = -1; sh_r = 0; sh_m = 0; }
    __syncthreads();
    int T = sh_T;
    int TT = (T < 0) ? 0 : T;
    u32* offi = offC + (size_t)img * NBT * NCH;
    u32* bti = basetot + (size_t)img * NBT;
    u32 cum = excl;
    int hi = NBT - 1 - tid * 4;
#pragma unroll
    for (int j = 0; j < 4; ++j) {
        int bin = hi - j;
        u32 c0 = reg[3 - j];
        if (bin > T) {
            u32 run = cum;
            for (int c = 0; c < NCH; ++c) {
                offi[(size_t)(bin - TT) * NCH + c] = run;
                run += Mi[(size_t)c * NBT + bin];
            }
            bti[bin] = (cum << 16) | c0;
        } else if (bin == T && T >= 0) {
            u32 run = TOPK;
            for (int c = 0; c < NCH; ++c) {
                offi[(size_t)(bin - TT) * NCH + c] = run;
                run += Mi[(size_t)c * NBT + bin];
            }
        }
        cum += c0;
    }
    u64* gk = gkeys + (size_t)img * GK;
    for (int i = tid; i < TOPK; i += 1024) gk[i] = 0ull;
    if (tid == 0) {
        tinfo[3 * img] = T;
        tinfo[3 * img + 1] = (int)sh_r;
        tinfo[3 * img + 2] = (int)sh_m;
    }
}

// ===== scatter: preload only R = NBT-TT compact offsets =====
__global__ __launch_bounds__(512) void k_scatter(const u64* __restrict__ surv,
                                                 const u32* __restrict__ cnt,
                                                 const int* __restrict__ tinfo,
                                                 const u32* __restrict__ offC,
                                                 u64* __restrict__ gkeys) {
    __shared__ u32 loff[NBT];
    int img = blockIdx.x / NCH, c = blockIdx.x % NCH;
    int tid = (int)threadIdx.x;
    int T = tinfo[3 * img];
    int TT = (T < 0) ? 0 : T;
    int R = NBT - TT;
    const u32* src = offC + (size_t)img * NBT * NCH;
    for (int i = tid; i < R; i += 512) loff[i] = src[(size_t)i * NCH + c];
    __syncthreads();
    u32 n = cnt[img];
    if (n > CAP) n = CAP;
    u32 chunk = (n + NCH - 1) / NCH;
    u32 lo = c * chunk, hiX = min(n, lo + chunk);
    const u64* sv = surv + (size_t)img * CAP;
    u64* gk = gkeys + (size_t)img * GK;
    for (u32 i = lo + tid; i < hiX; i += 512) {
        u64 kk = sv[i];
        int bb = binOf(kk);
        if (bb < TT) continue;
        u32 slot = atomicAdd(&loff[bb - TT], 1u);
        if (slot < GK) gk[slot] = kk;
    }
}

// ===== finalize: exact candidate ranks + within-segment ranks -> sorted =====
__global__ __launch_bounds__(1024) void k_fin(const int* __restrict__ tinfo,
                                              const u32* __restrict__ basetot,
                                              const u64* __restrict__ gkeys,
                                              u64* __restrict__ sorted) {
    __shared__ u64 up[TOPK];
    __shared__ u64 cnd[4096];
    int img = blockIdx.x, tid = (int)threadIdx.x;
    int T = tinfo[3 * img];
    u32 r = (u32)tinfo[3 * img + 1];
    u32 m = (u32)tinfo[3 * img + 2];
    if (m > 4096u) m = 4096u;
    const u64* gk = gkeys + (size_t)img * GK;
    for (int i = tid; i < TOPK; i += 1024) up[i] = gk[i];
    for (u32 i = tid; i < m; i += 1024) cnd[i] = gk[TOPK + i];
    __syncthreads();
    u64* dst = sorted + (size_t)img * TOPK;
    for (u32 i = tid; i < m; i += 1024) {
        u64 ki = cnd[i];
        u32 g = 0;
        for (u32 j = 0; j < m; ++j) g += (cnd[j] > ki) ? 1u : 0u;
        if (g < r) dst[TOPK - r + g] = ki;
    }
    u32 upper = TOPK - r;
    const u32* bti = basetot + (size_t)img * NBT;
    for (u32 s = tid; s < upper; s += 1024) {
        u64 kk = up[s];
        if (kk == 0ull) { dst[s] = 0ull; continue; }
        int bb = binOf(kk);
        u32 v = bti[bb];
        u32 base = v >> 16, cc = v & 0xFFFFu;
        u32 g = 0;
        for (u32 j = 0; j < cc; ++j) g += (up[base + j] > kk) ? 1u : 0u;
        dst[base + g] = kk;
    }
}

// ===== wave-parallel output: 2 keypoints/wave, 1 patch element/lane =====
__global__ __launch_bounds__(256) void k_out(const float* __restrict__ scores,
                                             const u64* __restrict__ sorted,
                                             float* __restrict__ out) {
    int gtid = blockIdx.x * 256 + (int)threadIdx.x;
    int wid = gtid >> 6;
    int l = gtid & 63;
    int half = l >> 5;
    int c = l & 31;
    int kpg = wid * 2 + half;
    int b = kpg >> 12;
    int kp = kpg & (TOPK - 1);
    const float* img = scores + (size_t)b * H * W;
    u64 key = sorted[(size_t)b * TOPK + kp];
    u32 idx = ~(u32)(key & 0xFFFFFFFFull);
    int ky = (int)(idx >> 10) & 1023, kx = (int)(idx & 1023);
    ky = min(max(ky, 2), H - 3);
    kx = min(max(kx, 2), W - 3);
    int row = c / 5, col = c % 5;
    float v = 0.0f;
    if (c < 25) v = img[(ky + row - 2) * W + (kx + col - 2)];
    float mx = (c < 25) ? v : -INFINITY;
#pragma unroll
    for (int mk = 1; mk < 32; mk <<= 1) mx = fmaxf(mx, __shfl_xor(mx, mk));
    float e = (c < 25) ? expf((v - mx) / 0.1f) : 0.0f;
    float dxv = (float)(col - 2), dyv = (float)(row - 2);
    float s0 = e, s1 = e * dxv, s2 = e * dyv;
#pragma unroll
    for (int mk = 1; mk < 32; mk <<= 1) {
        s0 += __shfl_xor(s0, mk);
        s1 += __shfl_xor(s1, mk);
        s2 += __shfl_xor(s2, mk);
    }
    float xr = s1 / s0, yr = s2 / s0;
    float ddx = (dxv - xr) * 0.5f, ddy = (dyv - yr) * 0.5f;
    float d = e * (ddx * ddx + ddy * ddy);
#pragma unroll
    for (int mk = 1; mk < 32; mk <<= 1) d += __shfl_xor(d, mk);
    float disp = d / s0;
    float kpx = ((float)kx + xr) / 1023.0f * 2.0f - 1.0f;
    float kpy = ((float)ky + yr) / 1023.0f * 2.0f - 1.0f;
    float px = (kpx + 1.0f) * 0.5f * 1023.0f;
    float py = (kpy + 1.0f) * 0.5f * 1023.0f;
    float fx = floorf(px), fy = floorf(py);
    float wx = px - fx, wy = py - fy;
    int x0 = (int)fminf(fmaxf(fx, 0.f), 1023.f);
    int x1 = (int)fminf(fmaxf(fx + 1.f, 0.f), 1023.f);
    int y0 = (int)fminf(fmaxf(fy, 0.f), 1023.f);
    int y1 = (int)fminf(fmaxf(fy + 1.f, 0.f), 1023.f);
    float bv = 0.0f;
    if (c < 4) {
        int xx = (c & 1) ? x1 : x0;
        int yy = (c >> 1) ? y1 : y0;
        bv = img[yy * W + xx];
    }
    int base = half * 32;
    float v00 = __shfl(bv, base + 0);
    float v01 = __shfl(bv, base + 1);
    float v10 = __shfl(bv, base + 2);
    float v11 = __shfl(bv, base + 3);
    float sc = v00 * (1.f - wx) * (1.f - wy) + v01 * wx * (1.f - wy) +
               v10 * (1.f - wx) * wy + v11 * wx * wy;
    if (c == 0) {
        size_t kb = (size_t)b * TOPK + kp;
        out[kb * 2 + 0] = kpx;
        out[kb * 2 + 1] = kpy;
        out[(size_t)B * TOPK * 2 + kb] = disp;
        out[(size_t)B * TOPK * 3 + kb] = sc;
    }
}

extern "C" void kernel_launch(void* const* d_in, const int* in_sizes, int n_in,
                              void* d_out, int out_size, void* d_ws, size_t ws_size,
                              hipStream_t stream) {
    const float* scores = (const float*)d_in[0];
    float* out = (float*)d_out;
    char* ws = (char*)d_ws;
    u64* surv = (u64*)ws;                                   // 8 MB
    u16* M = (u16*)(ws + 8388608);                          // 512 KB (u16)
    u32* offC = (u32*)(ws + 10485760);                      // 1 MB (compact-indexed)
    u32* basetot = (u32*)(ws + 14680064);                   // 128 KB
    u64* gkeys = (u64*)(ws + 15204352);                     // 1.31 MB
    u64* sorted = (u64*)(ws + 16515072);                    // 256 KB
    u32* cnt = (u32*)(ws + 16777216);                       // 32 B
    int* tinfo = (int*)(ws + 16777280);                     // 96 B

    hipMemsetAsync(cnt, 0, B * sizeof(u32), stream);

    k_nms<<<dim3(GDX, GDY, B), 512, 0, stream>>>(scores, surv, cnt);
    k_hist<<<B * NCH, 512, 0, stream>>>(surv, cnt, M);
    k_scan<<<B, 1024, 0, stream>>>(M, offC, basetot, tinfo, gkeys);
    k_scatter<<<B * NCH, 512, 0, stream>>>(surv, cnt, tinfo, offC, gkeys);
    k_fin<<<B, 1024, 0, stream>>>(tinfo, basetot, gkeys, sorted);
    k_out<<<(B * TOPK * 32) / 256, 256, 0, stream>>>(scores, sorted, out);
}

// Round 24
// 109.027 us; speedup vs baseline: 1.0879x; 1.0879x over previous
//
#include <hip/hip_runtime.h>
#include <math.h>

#define H 1024
#define W 1024
#define B 8
#define TOPK 4096
#define CAP 131072
#define NBT 8192
#define NCH 8
#define GK 20480
#define TILE_X 108
#define TILE_Y 108
#define GDX 10
#define GDY 10
#define SKCAP 2048

typedef unsigned long long u64;
typedef unsigned int u32;
typedef unsigned short u16;

// DPP lane shifts (VALU, no DS). wave_shr1 (0x138) == shfl_up(v,1);
// wave_shl1 (0x130) == shfl_down(v,1). bound_ctrl zero-fill at lanes 0/63 is
// harmless: those lanes own region cols {0,1}/{126,127}, excluded by extents.
__device__ __forceinline__ float dpp_up1(float v) {
    int r = __builtin_amdgcn_update_dpp(0, __float_as_int(v), 0x138, 0xF, 0xF, true);
    return __int_as_float(r);
}
__device__ __forceinline__ float dpp_dn1(float v) {
    int r = __builtin_amdgcn_update_dpp(0, __float_as_int(v), 0x130, 0xF, 0xF, true);
    return __int_as_float(r);
}

// Monotone bin index, fine-grained where survivor values cluster (v in [0.5,1)).
__device__ __forceinline__ int binOf(u64 key) {
    u32 fb = (u32)(key >> 32);
    u32 ex = fb >> 23;
    if (ex >= 0x7Fu) return NBT - 1;
    if (ex == 0x7Eu) {
        u32 m13 = (fb >> 10) & 0x1FFFu;
        return (m13 < 64u) ? 64 : (int)m13;
    }
    if (ex >= 0x6Eu) return (int)(ex - 0x6Eu + 47u);
    return 1;
}

// ================= Fused 3-round NMS + survivor compaction =================
#define ROUND_A(VR0, VR1, USE_SUPP)                                               \
    _Pragma("unroll") for (int i = 0; i < 16; ++i) {                              \
        int r = rbase + i;                                                        \
        if (r < (VR0) || r > (VR1)) continue;                                     \
        float x = svx[i], y = svy[i];                                             \
        if (USE_SUPP) {                                                           \
            u64 se = sp[r][0], so = sp[r][1];                                     \
            u32 s0 = (u32)(se >> lane) & 1u;                                      \
            u32 s1 = (u32)(so >> lane) & 1u;                                      \
            sbx |= s0 << i;                                                       \
            sby |= s1 << i;                                                       \
            if (s0) x = 0.0f;                                                     \
            if (s1) y = 0.0f;                                                     \
        }                                                                         \
        float ux = dpp_up1(x), uy = dpp_up1(y);                                   \
        float dxx = dpp_dn1(x), dyy = dpp_dn1(y);                                 \
        float m01 = fmaxf(x, y);                                                  \
        float h0 = fmaxf(fmaxf(ux, uy), fmaxf(m01, dxx));                         \
        float h1 = fmaxf(fmaxf(uy, m01), fmaxf(dxx, dyy));                        \
        h0r[i] = h0;                                                              \
        h1r[i] = h1;                                                              \
        if (i == 0 || i == 1 || i == 14 || i == 15) {                             \
            int k = (i < 2) ? i : i - 12;                                         \
            *(float2*)&hb[w * 4 + k][2 * lane] = make_float2(h0, h1);             \
        }                                                                         \
    }

// h-boundary gather shared by ROUND_B variants
#define GATHER_V()                                                                \
        float v0x, v0y, v1x, v1y, v3x, v3y, v4x, v4y;                             \
        if (i >= 2) { v0x = h0r[i - 2]; v0y = h1r[i - 2]; }                       \
        else { int k = (i == 0) ? 2 : 3;                                          \
               float2 t = *(const float2*)&hb[(w - 1) * 4 + k][2 * lane];         \
               v0x = t.x; v0y = t.y; }                                            \
        if (i >= 1) { v1x = h0r[i - 1]; v1y = h1r[i - 1]; }                       \
        else { float2 t = *(const float2*)&hb[(w - 1) * 4 + 3][2 * lane];         \
               v1x = t.x; v1y = t.y; }                                            \
        if (i <= 14) { v3x = h0r[i + 1]; v3y = h1r[i + 1]; }                      \
        else { float2 t = *(const float2*)&hb[(w + 1) * 4 + 0][2 * lane];         \
               v3x = t.x; v3y = t.y; }                                            \
        if (i <= 13) { v4x = h0r[i + 2]; v4y = h1r[i + 2]; }                      \
        else { int k = (i == 14) ? 0 : 1;                                         \
               float2 t = *(const float2*)&hb[(w + 1) * 4 + k][2 * lane];         \
               v4x = t.x; v4y = t.y; }

#define ROUND_B(VV0, VV1, USE_SUPP, FIRST)                                        \
    _Pragma("unroll") for (int i = 0; i < 16; ++i) {                              \
        int r = rbase + i;                                                        \
        if (r < (VV0) || r > (VV1)) continue;                                     \
        GATHER_V()                                                                \
        float vm0 = fmaxf(fmaxf(fmaxf(v0x, v1x), fmaxf(v3x, v4x)), h0r[i]);       \
        float vm1 = fmaxf(fmaxf(fmaxf(v0y, v1y), fmaxf(v3y, v4y)), h1r[i]);       \
        float x = svx[i], y = svy[i];                                             \
        bool sb0 = false, sb1 = false;                                            \
        if (USE_SUPP) {                                                           \
            sb0 = (sbx >> i) & 1u;                                                \
            sb1 = (sby >> i) & 1u;                                                \
            if (sb0) x = 0.0f;                                                    \
            if (sb1) y = 0.0f;                                                    \
        }                                                                         \
        int c0 = 2 * lane;                                                        \
        bool bit0 = (x == vm0) && !sb0 && (svx[i] != -INFINITY) &&                \
                    c0 >= (VV0) && c0 <= (VV1);                                   \
        bool bit1 = (y == vm1) && !sb1 && (svy[i] != -INFINITY) &&                \
                    (c0 + 1) >= (VV0) && (c0 + 1) <= (VV1);                       \
        u64 bE = __ballot(bit0), bO = __ballot(bit1);                             \
        if (lane == 0) {                                                          \
            u64 ne = ((FIRST) ? 0ull : ma[r][0]) | bE;                            \
            u64 no = ((FIRST) ? 0ull : ma[r][1]) | bO;                            \
            ma[r][0] = ne;                                                        \
            ma[r][1] = no;                                                        \
        }                                                                         \
    }

// Final round fused with survivor extraction: each lane's final mask bit =
// (old ma bit) | (its own new-max bit); no ballot, no merge write, no extra
// barrier or re-read loop. Col/border filters identical to old extraction.
#define ROUND_B_FINAL()                                                           \
    _Pragma("unroll") for (int i = 0; i < 16; ++i) {                              \
        int r = rbase + i;                                                        \
        if (r < 10 || r > 117) continue;                                          \
        GATHER_V()                                                                \
        float vm0 = fmaxf(fmaxf(fmaxf(v0x, v1x), fmaxf(v3x, v4x)), h0r[i]);       \
        float vm1 = fmaxf(fmaxf(fmaxf(v0y, v1y), fmaxf(v3y, v4y)), h1r[i]);       \
        float x = svx[i], y = svy[i];                                             \
        bool sb0 = (sbx >> i) & 1u;                                               \
        bool sb1 = (sby >> i) & 1u;                                               \
        if (sb0) x = 0.0f;                                                        \
        if (sb1) y = 0.0f;                                                        \
        int c0 = 2 * lane;                                                        \
        bool bit0 = (x == vm0) && !sb0 && (svx[i] != -INFINITY);                  \
        bool bit1 = (y == vm1) && !sb1 && (svy[i] != -INFINITY);                  \
        u64 me_old = ma[r][0], mo_old = ma[r][1];                                 \
        bool fin0 = bit0 || (((me_old >> lane) & 1ull) != 0);                     \
        bool fin1 = bit1 || (((mo_old >> lane) & 1ull) != 0);                     \
        int gy = gy0 + r;                                                         \
        if (c0 >= 10 && c0 <= 117 && fin0 && svx[i] > 0.0f &&                     \
            gx >= 2 && gx < W - 2 && gy >= 2 && gy < H - 2) {                     \
            u32 pos = atomicAdd(&lcnt, 1u);                                       \
            if (pos < SKCAP) {                                                    \
                u32 p = (u32)(gy * W + gx);                                       \
                skey[pos] = ((u64)__float_as_uint(svx[i]) << 32) | (u64)(~p);     \
            }                                                                     \
        }                                                                         \
        if (c0 + 1 >= 10 && c0 + 1 <= 117 && fin1 && svy[i] > 0.0f &&             \
            gx + 1 >= 2 && gx + 1 < W - 2 && gy >= 2 && gy < H - 2) {             \
            u32 pos = atomicAdd(&lcnt, 1u);                                       \
            if (pos < SKCAP) {                                                    \
                u32 p = (u32)(gy * W + gx + 1);                                   \
                skey[pos] = ((u64)__float_as_uint(svy[i]) << 32) | (u64)(~p);     \
            }                                                                     \
        }                                                                         \
    }

#define DILATE(R0, R1)                                                            \
    if (tid >= (R0) && tid <= (R1)) {                                             \
        int rr = tid;                                                             \
        u64 e = ma[rr - 2][0] | ma[rr - 1][0] | ma[rr][0] | ma[rr + 1][0] |       \
                ma[rr + 2][0];                                                    \
        u64 o = ma[rr - 2][1] | ma[rr - 1][1] | ma[rr][1] | ma[rr + 1][1] |       \
                ma[rr + 2][1];                                                    \
        sp[rr][0] = e | (e << 1) | (e >> 1) | o | (o << 1);                       \
        sp[rr][1] = o | (o << 1) | (o >> 1) | e | (e >> 1);                       \
    }

__global__ __launch_bounds__(512) void k_nms(const float* __restrict__ scores,
                                             u64* __restrict__ surv,
                                             u32* __restrict__ cnt) {
    __shared__ float hb[32][128];                  // 16 KB
    __shared__ __align__(16) u64 ma[128][2];       // [E,O] interleaved
    __shared__ __align__(16) u64 sp[128][2];
    __shared__ u64 skey[SKCAP];                    // 16 KB (separate; hb live)
    __shared__ u32 lcnt, gbase;
    const int b = blockIdx.z;
    const int gx0 = blockIdx.x * TILE_X - 10;
    const int gy0 = blockIdx.y * TILE_Y - 10;
    const float* img = scores + (size_t)b * H * W;
    const int tid = (int)threadIdx.x, lane = tid & 63, w = tid >> 6, rbase = w * 16;
    const int gx = gx0 + 2 * lane;
    if (tid == 0) lcnt = 0;

    float svx[16], svy[16], h0r[16], h1r[16];
    u32 sbx = 0, sby = 0;
#pragma unroll
    for (int i = 0; i < 16; ++i) {
        int gy = gy0 + rbase + i;
        float x = -INFINITY, y = -INFINITY;
        if (gy >= 0 && gy < H) {
            const float* row = img + (size_t)gy * W;
            if (gx >= 0 && gx + 1 < W) {
                float2 t = *(const float2*)(row + gx);
                x = t.x; y = t.y;
            } else if (gx >= 0 && gx < W) {
                x = row[gx];
            }
        }
        svx[i] = x; svy[i] = y;
    }

    ROUND_A(0, 127, false)
    __syncthreads();
    ROUND_B(2, 125, false, 1)
    __syncthreads();
    DILATE(4, 123)
    __syncthreads();
    sbx = 0; sby = 0;
    ROUND_A(4, 123, true)
    __syncthreads();
    ROUND_B(6, 121, true, 0)
    __syncthreads();
    DILATE(8, 119)
    __syncthreads();
    sbx = 0; sby = 0;
    ROUND_A(8, 119, true)
    __syncthreads();
    ROUND_B_FINAL()
    __syncthreads();
    u32 nk = lcnt < SKCAP ? lcnt : SKCAP;
    if (tid == 0) gbase = nk ? atomicAdd(&cnt[b], nk) : 0u;
    __syncthreads();
    for (u32 i = tid; i < nk; i += 512)
        surv[(size_t)b * CAP + gbase + i] = skey[i];
}

// ===== per-chunk private histograms; M (u16) layout [img][chunk][bin] =====
__global__ __launch_bounds__(512) void k_hist(const u64* __restrict__ surv,
                                              const u32* __restrict__ cnt,
                                              u16* __restrict__ M) {
    __shared__ u32 h[NBT];
    int img = blockIdx.x / NCH, c = blockIdx.x % NCH;
    int tid = (int)threadIdx.x;
    for (int i = tid; i < NBT; i += 512) h[i] = 0;
    __syncthreads();
    u32 n = cnt[img];
    if (n > CAP) n = CAP;
    u32 chunk = (n + NCH - 1) / NCH;
    u32 lo = c * chunk, hi = min(n, lo + chunk);
    const u64* sv = surv + (size_t)img * CAP;
    for (u32 i = lo + tid; i < hi; i += 512) atomicAdd(&h[binOf(sv[i])], 1u);
    __syncthreads();
    u16* dst = M + ((size_t)img * NCH + c) * NBT;
    for (int i = tid; i < NBT; i += 512) dst[i] = (u16)h[i];
}

// ===== scan v3: register accumulate (ushort4 loads) + shuffle scan =====
__global__ __launch_bounds__(1024) void k_scan(const u16* __restrict__ M,
                                               u32* __restrict__ offC,
                                               u32* __restrict__ basetot,
                                               int* __restrict__ tinfo,
                                               u64* __restrict__ gkeys) {
    __shared__ u32 wsum[16];
    __shared__ u32 sh_ntot;
    __shared__ int sh_T;
    __shared__ u32 sh_r, sh_m;
    int img = blockIdx.x, tid = (int)threadIdx.x;
    const u16* Mi = M + (size_t)img * NCH * NBT;
    const int base = NBT - 8 - tid * 8;
    u32 reg[8] = {0, 0, 0, 0, 0, 0, 0, 0};
    for (int c = 0; c < NCH; ++c) {
        const u16* p = Mi + (size_t)c * NBT + base;
        ushort4 a = *(const ushort4*)(p);
        ushort4 b2 = *(const ushort4*)(p + 4);
        reg[0] += a.x; reg[1] += a.y; reg[2] += a.z; reg[3] += a.w;
        reg[4] += b2.x; reg[5] += b2.y; reg[6] += b2.z; reg[7] += b2.w;
    }
    u32 tot = 0;
#pragma unroll
    for (int j = 0; j < 8; ++j) tot += reg[j];
    u32 x = tot;
    int ln = tid & 63, wv = tid >> 6;
#pragma unroll
    for (int off = 1; off < 64; off <<= 1) {
        u32 v = (u32)__shfl_up((int)x, off);
        if (ln >= off) x += v;
    }
    if (ln == 63) wsum[wv] = x;
    __syncthreads();
    if (tid < 16) {
        u32 wval = wsum[tid];
        u32 wx = wval;
        for (int off = 1; off < 16; off <<= 1) {
            u32 v = (u32)__shfl_up((int)wx, off);
            if (tid >= off) wx += v;
        }
        wsum[tid] = wx - wval;
        if (tid == 15) sh_ntot = wx;
    }
    __syncthreads();
    u32 incl = x + wsum[wv];
    u32 excl = incl - tot;
    u32 ntot = sh_ntot;
    if (ntot > TOPK) {
        if (excl < TOPK && TOPK <= incl) {
            u32 cum = excl;
#pragma unroll
            for (int j = 0; j < 8; ++j) {
                u32 cj = reg[7 - j];
                if (cum + cj >= TOPK) {
                    sh_T = NBT - 1 - tid * 8 - j;
                    sh_r = TOPK - cum;
                    sh_m = cj;
                    break;
                }
                cum += cj;
            }
        }
    } else if (tid == 0) { sh_T = -1; sh_r = 0; sh_m = 0; }
    __syncthreads();
    int T = sh_T;
    int TT = (T < 0) ? 0 : T;
    u32* offi = offC + (size_t)img * NBT * NCH;
    u32* bti = basetot + (size_t)img * NBT;
    u32 cum = excl;
    int hi = NBT - 1 - tid * 8;
#pragma unroll
    for (int j = 0; j < 8; ++j) {
        int bin = hi - j;
        u32 c0 = reg[7 - j];
        if (bin > T) {
            u32 run = cum;
            for (int c = 0; c < NCH; ++c) {
                offi[(size_t)(bin - TT) * NCH + c] = run;
                run += Mi[(size_t)c * NBT + bin];
            }
            bti[bin] = (cum << 16) | c0;
        } else if (bin == T && T >= 0) {
            u32 run = TOPK;
            for (int c = 0; c < NCH; ++c) {
                offi[(size_t)(bin - TT) * NCH + c] = run;
                run += Mi[(size_t)c * NBT + bin];
            }
        }
        cum += c0;
    }
    u64* gk = gkeys + (size_t)img * GK;
    for (int i = tid; i < TOPK; i += 1024) gk[i] = 0ull;
    if (tid == 0) {
        tinfo[3 * img] = T;
        tinfo[3 * img + 1] = (int)sh_r;
        tinfo[3 * img + 2] = (int)sh_m;
    }
}

// ===== scatter: preload only R = NBT-TT compact offsets =====
__global__ __launch_bounds__(512) void k_scatter(const u64* __restrict__ surv,
                                                 const u32* __restrict__ cnt,
                                                 const int* __restrict__ tinfo,
                                                 const u32* __restrict__ offC,
                                                 u64* __restrict__ gkeys) {
    __shared__ u32 loff[NBT];
    int img = blockIdx.x / NCH, c = blockIdx.x % NCH;
    int tid = (int)threadIdx.x;
    int T = tinfo[3 * img];
    int TT = (T < 0) ? 0 : T;
    int R = NBT - TT;
    const u32* src = offC + (size_t)img * NBT * NCH;
    for (int i = tid; i < R; i += 512) loff[i] = src[(size_t)i * NCH + c];
    __syncthreads();
    u32 n = cnt[img];
    if (n > CAP) n = CAP;
    u32 chunk = (n + NCH - 1) / NCH;
    u32 lo = c * chunk, hiX = min(n, lo + chunk);
    const u64* sv = surv + (size_t)img * CAP;
    u64* gk = gkeys + (size_t)img * GK;
    for (u32 i = lo + tid; i < hiX; i += 512) {
        u64 kk = sv[i];
        int bb = binOf(kk);
        if (bb < TT) continue;
        u32 slot = atomicAdd(&loff[bb - TT], 1u);
        if (slot < GK) gk[slot] = kk;
    }
}

// ===== finalize: exact candidate ranks + within-segment ranks -> sorted =====
__global__ __launch_bounds__(1024) void k_fin(const int* __restrict__ tinfo,
                                              const u32* __restrict__ basetot,
                                              const u64* __restrict__ gkeys,
                                              u64* __restrict__ sorted) {
    __shared__ u64 up[TOPK];
    __shared__ u64 cnd[4096];
    int img = blockIdx.x, tid = (int)threadIdx.x;
    int T = tinfo[3 * img];
    u32 r = (u32)tinfo[3 * img + 1];
    u32 m = (u32)tinfo[3 * img + 2];
    if (m > 4096u) m = 4096u;
    const u64* gk = gkeys + (size_t)img * GK;
    for (int i = tid; i < TOPK; i += 1024) up[i] = gk[i];
    for (u32 i = tid; i < m; i += 1024) cnd[i] = gk[TOPK + i];
    __syncthreads();
    u64* dst = sorted + (size_t)img * TOPK;
    for (u32 i = tid; i < m; i += 1024) {
        u64 ki = cnd[i];
        u32 g = 0;
        for (u32 j = 0; j < m; ++j) g += (cnd[j] > ki) ? 1u : 0u;
        if (g < r) dst[TOPK - r + g] = ki;
    }
    u32 upper = TOPK - r;
    const u32* bti = basetot + (size_t)img * NBT;
    for (u32 s = tid; s < upper; s += 1024) {
        u64 kk = up[s];
        if (kk == 0ull) { dst[s] = 0ull; continue; }
        int bb = binOf(kk);
        u32 v = bti[bb];
        u32 base = v >> 16, cc = v & 0xFFFFu;
        u32 g = 0;
        for (u32 j = 0; j < cc; ++j) g += (up[base + j] > kk) ? 1u : 0u;
        dst[base + g] = kk;
    }
}

// ===== wave-parallel output: 2 keypoints/wave, 1 patch element/lane =====
__global__ __launch_bounds__(256) void k_out(const float* __restrict__ scores,
                                             const u64* __restrict__ sorted,
                                             float* __restrict__ out) {
    int gtid = blockIdx.x * 256 + (int)threadIdx.x;
    int wid = gtid >> 6;
    int l = gtid & 63;
    int half = l >> 5;
    int c = l & 31;
    int kpg = wid * 2 + half;
    int b = kpg >> 12;
    int kp = kpg & (TOPK - 1);
    const float* img = scores + (size_t)b * H * W;
    u64 key = sorted[(size_t)b * TOPK + kp];
    u32 idx = ~(u32)(key & 0xFFFFFFFFull);
    int ky = (int)(idx >> 10) & 1023, kx = (int)(idx & 1023);
    ky = min(max(ky, 2), H - 3);
    kx = min(max(kx, 2), W - 3);
    int row = c / 5, col = c % 5;
    float v = 0.0f;
    if (c < 25) v = img[(ky + row - 2) * W + (kx + col - 2)];
    float mx = (c < 25) ? v : -INFINITY;
#pragma unroll
    for (int mk = 1; mk < 32; mk <<= 1) mx = fmaxf(mx, __shfl_xor(mx, mk));
    float e = (c < 25) ? expf((v - mx) / 0.1f) : 0.0f;
    float dxv = (float)(col - 2), dyv = (float)(row - 2);
    float s0 = e, s1 = e * dxv, s2 = e * dyv;
#pragma unroll
    for (int mk = 1; mk < 32; mk <<= 1) {
        s0 += __shfl_xor(s0, mk);
        s1 += __shfl_xor(s1, mk);
        s2 += __shfl_xor(s2, mk);
    }
    float xr = s1 / s0, yr = s2 / s0;
    float ddx = (dxv - xr) * 0.5f, ddy = (dyv - yr) * 0.5f;
    float d = e * (ddx * ddx + ddy * ddy);
#pragma unroll
    for (int mk = 1; mk < 32; mk <<= 1) d += __shfl_xor(d, mk);
    float disp = d / s0;
    float kpx = ((float)kx + xr) / 1023.0f * 2.0f - 1.0f;
    float kpy = ((float)ky + yr) / 1023.0f * 2.0f - 1.0f;
    float px = (kpx + 1.0f) * 0.5f * 1023.0f;
    float py = (kpy + 1.0f) * 0.5f * 1023.0f;
    float fx = floorf(px), fy = floorf(py);
    float wx = px - fx, wy = py - fy;
    int x0 = (int)fminf(fmaxf(fx, 0.f), 1023.f);
    int x1 = (int)fminf(fmaxf(fx + 1.f, 0.f), 1023.f);
    int y0 = (int)fminf(fmaxf(fy, 0.f), 1023.f);
    int y1 = (int)fminf(fmaxf(fy + 1.f, 0.f), 1023.f);
    float bv = 0.0f;
    if (c < 4) {
        int xx = (c & 1) ? x1 : x0;
        int yy = (c >> 1) ? y1 : y0;
        bv = img[yy * W + xx];
    }
    int base = half * 32;
    float v00 = __shfl(bv, base + 0);
    float v01 = __shfl(bv, base + 1);
    float v10 = __shfl(bv, base + 2);
    float v11 = __shfl(bv, base + 3);
    float sc = v00 * (1.f - wx) * (1.f - wy) + v01 * wx * (1.f - wy) +
               v10 * (1.f - wx) * wy + v11 * wx * wy;
    if (c == 0) {
        size_t kb = (size_t)b * TOPK + kp;
        out[kb * 2 + 0] = kpx;
        out[kb * 2 + 1] = kpy;
        out[(size_t)B * TOPK * 2 + kb] = disp;
        out[(size_t)B * TOPK * 3 + kb] = sc;
    }
}

extern "C" void kernel_launch(void* const* d_in, const int* in_sizes, int n_in,
                              void* d_out, int out_size, void* d_ws, size_t ws_size,
                              hipStream_t stream) {
    const float* scores = (const float*)d_in[0];
    float* out = (float*)d_out;
    char* ws = (char*)d_ws;
    u64* surv = (u64*)ws;                                   // 8 MB
    u16* M = (u16*)(ws + 8388608);                          // 1 MB (u16)
    u32* offC = (u32*)(ws + 10485760);                      // 2 MB (compact-indexed)
    u32* basetot = (u32*)(ws + 14680064);                   // 256 KB
    u64* gkeys = (u64*)(ws + 15204352);                     // 1.31 MB
    u64* sorted = (u64*)(ws + 16515072);                    // 256 KB
    u32* cnt = (u32*)(ws + 16777216);                       // 32 B
    int* tinfo = (int*)(ws + 16777280);                     // 96 B

    hipMemsetAsync(cnt, 0, B * sizeof(u32), stream);

    k_nms<<<dim3(GDX, GDY, B), 512, 0, stream>>>(scores, surv, cnt);
    k_hist<<<B * NCH, 512, 0, stream>>>(surv, cnt, M);
    k_scan<<<B, 1024, 0, stream>>>(M, offC, basetot, tinfo, gkeys);
    k_scatter<<<B * NCH, 512, 0, stream>>>(surv, cnt, tinfo, offC, gkeys);
    k_fin<<<B, 1024, 0, stream>>>(tinfo, basetot, gkeys, sorted);
    k_out<<<(B * TOPK * 32) / 256, 256, 0, stream>>>(scores, sorted, out);
}

// Round 25
// 105.797 us; speedup vs baseline: 1.1211x; 1.0305x over previous
//
#include <hip/hip_runtime.h>
#include <math.h>

#define H 1024
#define W 1024
#define B 8
#define TOPK 4096
#define CAP 131072
#define NBT 8192
#define NCH 16
#define GK 20480
#define TILE_X 108
#define TILE_Y 108
#define GDX 10
#define GDY 10
#define SKCAP 2048

typedef unsigned long long u64;
typedef unsigned int u32;
typedef unsigned short u16;

// DPP lane shifts (VALU, no DS). wave_shr1 (0x138) == shfl_up(v,1);
// wave_shl1 (0x130) == shfl_down(v,1). bound_ctrl zero-fill at lanes 0/63 is
// harmless: those lanes own region cols {0,1}/{126,127}, excluded by extents.
__device__ __forceinline__ float dpp_up1(float v) {
    int r = __builtin_amdgcn_update_dpp(0, __float_as_int(v), 0x138, 0xF, 0xF, true);
    return __int_as_float(r);
}
__device__ __forceinline__ float dpp_dn1(float v) {
    int r = __builtin_amdgcn_update_dpp(0, __float_as_int(v), 0x130, 0xF, 0xF, true);
    return __int_as_float(r);
}

// Monotone bin index, fine-grained where survivor values cluster (v in [0.5,1)).
__device__ __forceinline__ int binOf(u64 key) {
    u32 fb = (u32)(key >> 32);
    u32 ex = fb >> 23;
    if (ex >= 0x7Fu) return NBT - 1;
    if (ex == 0x7Eu) {
        u32 m13 = (fb >> 10) & 0x1FFFu;
        return (m13 < 64u) ? 64 : (int)m13;
    }
    if (ex >= 0x6Eu) return (int)(ex - 0x6Eu + 47u);
    return 1;
}

// ================= Fused 3-round NMS + survivor compaction (round-24 verbatim) =================
#define ROUND_A(VR0, VR1, USE_SUPP)                                               \
    _Pragma("unroll") for (int i = 0; i < 16; ++i) {                              \
        int r = rbase + i;                                                        \
        if (r < (VR0) || r > (VR1)) continue;                                     \
        float x = svx[i], y = svy[i];                                             \
        if (USE_SUPP) {                                                           \
            u64 se = sp[r][0], so = sp[r][1];                                     \
            u32 s0 = (u32)(se >> lane) & 1u;                                      \
            u32 s1 = (u32)(so >> lane) & 1u;                                      \
            sbx |= s0 << i;                                                       \
            sby |= s1 << i;                                                       \
            if (s0) x = 0.0f;                                                     \
            if (s1) y = 0.0f;                                                     \
        }                                                                         \
        float ux = dpp_up1(x), uy = dpp_up1(y);                                   \
        float dxx = dpp_dn1(x), dyy = dpp_dn1(y);                                 \
        float m01 = fmaxf(x, y);                                                  \
        float h0 = fmaxf(fmaxf(ux, uy), fmaxf(m01, dxx));                         \
        float h1 = fmaxf(fmaxf(uy, m01), fmaxf(dxx, dyy));                        \
        h0r[i] = h0;                                                              \
        h1r[i] = h1;                                                              \
        if (i == 0 || i == 1 || i == 14 || i == 15) {                             \
            int k = (i < 2) ? i : i - 12;                                         \
            *(float2*)&hb[w * 4 + k][2 * lane] = make_float2(h0, h1);             \
        }                                                                         \
    }

#define GATHER_V()                                                                \
        float v0x, v0y, v1x, v1y, v3x, v3y, v4x, v4y;                             \
        if (i >= 2) { v0x = h0r[i - 2]; v0y = h1r[i - 2]; }                       \
        else { int k = (i == 0) ? 2 : 3;                                          \
               float2 t = *(const float2*)&hb[(w - 1) * 4 + k][2 * lane];         \
               v0x = t.x; v0y = t.y; }                                            \
        if (i >= 1) { v1x = h0r[i - 1]; v1y = h1r[i - 1]; }                       \
        else { float2 t = *(const float2*)&hb[(w - 1) * 4 + 3][2 * lane];         \
               v1x = t.x; v1y = t.y; }                                            \
        if (i <= 14) { v3x = h0r[i + 1]; v3y = h1r[i + 1]; }                      \
        else { float2 t = *(const float2*)&hb[(w + 1) * 4 + 0][2 * lane];         \
               v3x = t.x; v3y = t.y; }                                            \
        if (i <= 13) { v4x = h0r[i + 2]; v4y = h1r[i + 2]; }                      \
        else { int k = (i == 14) ? 0 : 1;                                         \
               float2 t = *(const float2*)&hb[(w + 1) * 4 + k][2 * lane];         \
               v4x = t.x; v4y = t.y; }

#define ROUND_B(VV0, VV1, USE_SUPP, FIRST)                                        \
    _Pragma("unroll") for (int i = 0; i < 16; ++i) {                              \
        int r = rbase + i;                                                        \
        if (r < (VV0) || r > (VV1)) continue;                                     \
        GATHER_V()                                                                \
        float vm0 = fmaxf(fmaxf(fmaxf(v0x, v1x), fmaxf(v3x, v4x)), h0r[i]);       \
        float vm1 = fmaxf(fmaxf(fmaxf(v0y, v1y), fmaxf(v3y, v4y)), h1r[i]);       \
        float x = svx[i], y = svy[i];                                             \
        bool sb0 = false, sb1 = false;                                            \
        if (USE_SUPP) {                                                           \
            sb0 = (sbx >> i) & 1u;                                                \
            sb1 = (sby >> i) & 1u;                                                \
            if (sb0) x = 0.0f;                                                    \
            if (sb1) y = 0.0f;                                                    \
        }                                                                         \
        int c0 = 2 * lane;                                                        \
        bool bit0 = (x == vm0) && !sb0 && (svx[i] != -INFINITY) &&                \
                    c0 >= (VV0) && c0 <= (VV1);                                   \
        bool bit1 = (y == vm1) && !sb1 && (svy[i] != -INFINITY) &&                \
                    (c0 + 1) >= (VV0) && (c0 + 1) <= (VV1);                       \
        u64 bE = __ballot(bit0), bO = __ballot(bit1);                             \
        if (lane == 0) {                                                          \
            u64 ne = ((FIRST) ? 0ull : ma[r][0]) | bE;                            \
            u64 no = ((FIRST) ? 0ull : ma[r][1]) | bO;                            \
            ma[r][0] = ne;                                                        \
            ma[r][1] = no;                                                        \
        }                                                                         \
    }

#define ROUND_B_FINAL()                                                           \
    _Pragma("unroll") for (int i = 0; i < 16; ++i) {                              \
        int r = rbase + i;                                                        \
        if (r < 10 || r > 117) continue;                                          \
        GATHER_V()                                                                \
        float vm0 = fmaxf(fmaxf(fmaxf(v0x, v1x), fmaxf(v3x, v4x)), h0r[i]);       \
        float vm1 = fmaxf(fmaxf(fmaxf(v0y, v1y), fmaxf(v3y, v4y)), h1r[i]);       \
        float x = svx[i], y = svy[i];                                             \
        bool sb0 = (sbx >> i) & 1u;                                               \
        bool sb1 = (sby >> i) & 1u;                                               \
        if (sb0) x = 0.0f;                                                        \
        if (sb1) y = 0.0f;                                                        \
        int c0 = 2 * lane;                                                        \
        bool bit0 = (x == vm0) && !sb0 && (svx[i] != -INFINITY);                  \
        bool bit1 = (y == vm1) && !sb1 && (svy[i] != -INFINITY);                  \
        u64 me_old = ma[r][0], mo_old = ma[r][1];                                 \
        bool fin0 = bit0 || (((me_old >> lane) & 1ull) != 0);                     \
        bool fin1 = bit1 || (((mo_old >> lane) & 1ull) != 0);                     \
        int gy = gy0 + r;                                                         \
        if (c0 >= 10 && c0 <= 117 && fin0 && svx[i] > 0.0f &&                     \
            gx >= 2 && gx < W - 2 && gy >= 2 && gy < H - 2) {                     \
            u32 pos = atomicAdd(&lcnt, 1u);                                       \
            if (pos < SKCAP) {                                                    \
                u32 p = (u32)(gy * W + gx);                                       \
                skey[pos] = ((u64)__float_as_uint(svx[i]) << 32) | (u64)(~p);     \
            }                                                                     \
        }                                                                         \
        if (c0 + 1 >= 10 && c0 + 1 <= 117 && fin1 && svy[i] > 0.0f &&             \
            gx + 1 >= 2 && gx + 1 < W - 2 && gy >= 2 && gy < H - 2) {             \
            u32 pos = atomicAdd(&lcnt, 1u);                                       \
            if (pos < SKCAP) {                                                    \
                u32 p = (u32)(gy * W + gx + 1);                                   \
                skey[pos] = ((u64)__float_as_uint(svy[i]) << 32) | (u64)(~p);     \
            }                                                                     \
        }                                                                         \
    }

#define DILATE(R0, R1)                                                            \
    if (tid >= (R0) && tid <= (R1)) {                                             \
        int rr = tid;                                                             \
        u64 e = ma[rr - 2][0] | ma[rr - 1][0] | ma[rr][0] | ma[rr + 1][0] |       \
                ma[rr + 2][0];                                                    \
        u64 o = ma[rr - 2][1] | ma[rr - 1][1] | ma[rr][1] | ma[rr + 1][1] |       \
                ma[rr + 2][1];                                                    \
        sp[rr][0] = e | (e << 1) | (e >> 1) | o | (o << 1);                       \
        sp[rr][1] = o | (o << 1) | (o >> 1) | e | (e >> 1);                       \
    }

__global__ __launch_bounds__(512) void k_nms(const float* __restrict__ scores,
                                             u64* __restrict__ surv,
                                             u32* __restrict__ cnt) {
    __shared__ float hb[32][128];                  // 16 KB
    __shared__ __align__(16) u64 ma[128][2];       // [E,O] interleaved
    __shared__ __align__(16) u64 sp[128][2];
    __shared__ u64 skey[SKCAP];                    // 16 KB (separate; hb live)
    __shared__ u32 lcnt, gbase;
    const int b = blockIdx.z;
    const int gx0 = blockIdx.x * TILE_X - 10;
    const int gy0 = blockIdx.y * TILE_Y - 10;
    const float* img = scores + (size_t)b * H * W;
    const int tid = (int)threadIdx.x, lane = tid & 63, w = tid >> 6, rbase = w * 16;
    const int gx = gx0 + 2 * lane;
    if (tid == 0) lcnt = 0;

    float svx[16], svy[16], h0r[16], h1r[16];
    u32 sbx = 0, sby = 0;
#pragma unroll
    for (int i = 0; i < 16; ++i) {
        int gy = gy0 + rbase + i;
        float x = -INFINITY, y = -INFINITY;
        if (gy >= 0 && gy < H) {
            const float* row = img + (size_t)gy * W;
            if (gx >= 0 && gx + 1 < W) {
                float2 t = *(const float2*)(row + gx);
                x = t.x; y = t.y;
            } else if (gx >= 0 && gx < W) {
                x = row[gx];
            }
        }
        svx[i] = x; svy[i] = y;
    }

    ROUND_A(0, 127, false)
    __syncthreads();
    ROUND_B(2, 125, false, 1)
    __syncthreads();
    DILATE(4, 123)
    __syncthreads();
    sbx = 0; sby = 0;
    ROUND_A(4, 123, true)
    __syncthreads();
    ROUND_B(6, 121, true, 0)
    __syncthreads();
    DILATE(8, 119)
    __syncthreads();
    sbx = 0; sby = 0;
    ROUND_A(8, 119, true)
    __syncthreads();
    ROUND_B_FINAL()
    __syncthreads();
    u32 nk = lcnt < SKCAP ? lcnt : SKCAP;
    if (tid == 0) gbase = nk ? atomicAdd(&cnt[b], nk) : 0u;
    __syncthreads();
    for (u32 i = tid; i < nk; i += 512)
        surv[(size_t)b * CAP + gbase + i] = skey[i];
}

// ===== per-chunk private histograms; M (u16) layout [img][chunk][bin] =====
__global__ __launch_bounds__(512) void k_hist(const u64* __restrict__ surv,
                                              const u32* __restrict__ cnt,
                                              u16* __restrict__ M) {
    __shared__ u32 h[NBT];
    int img = blockIdx.x / NCH, c = blockIdx.x % NCH;
    int tid = (int)threadIdx.x;
    for (int i = tid; i < NBT; i += 512) h[i] = 0;
    __syncthreads();
    u32 n = cnt[img];
    if (n > CAP) n = CAP;
    u32 chunk = (n + NCH - 1) / NCH;
    u32 lo = c * chunk, hi = min(n, lo + chunk);
    const u64* sv = surv + (size_t)img * CAP;
    for (u32 i = lo + tid; i < hi; i += 512) atomicAdd(&h[binOf(sv[i])], 1u);
    __syncthreads();
    u16* dst = M + ((size_t)img * NCH + c) * NBT;
    for (int i = tid; i < NBT; i += 512) dst[i] = (u16)h[i];
}

// ===== scan: register accumulate (ushort4 loads) + shuffle scan =====
__global__ __launch_bounds__(1024) void k_scan(const u16* __restrict__ M,
                                               u32* __restrict__ offC,
                                               u32* __restrict__ basetot,
                                               int* __restrict__ tinfo,
                                               u64* __restrict__ gkeys) {
    __shared__ u32 wsum[16];
    __shared__ u32 sh_ntot;
    __shared__ int sh_T;
    __shared__ u32 sh_r, sh_m;
    int img = blockIdx.x, tid = (int)threadIdx.x;
    const u16* Mi = M + (size_t)img * NCH * NBT;
    const int base = NBT - 8 - tid * 8;
    u32 reg[8] = {0, 0, 0, 0, 0, 0, 0, 0};
    for (int c = 0; c < NCH; ++c) {
        const u16* p = Mi + (size_t)c * NBT + base;
        ushort4 a = *(const ushort4*)(p);
        ushort4 b2 = *(const ushort4*)(p + 4);
        reg[0] += a.x; reg[1] += a.y; reg[2] += a.z; reg[3] += a.w;
        reg[4] += b2.x; reg[5] += b2.y; reg[6] += b2.z; reg[7] += b2.w;
    }
    u32 tot = 0;
#pragma unroll
    for (int j = 0; j < 8; ++j) tot += reg[j];
    u32 x = tot;
    int ln = tid & 63, wv = tid >> 6;
#pragma unroll
    for (int off = 1; off < 64; off <<= 1) {
        u32 v = (u32)__shfl_up((int)x, off);
        if (ln >= off) x += v;
    }
    if (ln == 63) wsum[wv] = x;
    __syncthreads();
    if (tid < 16) {
        u32 wval = wsum[tid];
        u32 wx = wval;
        for (int off = 1; off < 16; off <<= 1) {
            u32 v = (u32)__shfl_up((int)wx, off);
            if (tid >= off) wx += v;
        }
        wsum[tid] = wx - wval;
        if (tid == 15) sh_ntot = wx;
    }
    __syncthreads();
    u32 incl = x + wsum[wv];
    u32 excl = incl - tot;
    u32 ntot = sh_ntot;
    if (ntot > TOPK) {
        if (excl < TOPK && TOPK <= incl) {
            u32 cum = excl;
#pragma unroll
            for (int j = 0; j < 8; ++j) {
                u32 cj = reg[7 - j];
                if (cum + cj >= TOPK) {
                    sh_T = NBT - 1 - tid * 8 - j;
                    sh_r = TOPK - cum;
                    sh_m = cj;
                    break;
                }
                cum += cj;
            }
        }
    } else if (tid == 0) { sh_T = -1; sh_r = 0; sh_m = 0; }
    __syncthreads();
    int T = sh_T;
    int TT = (T < 0) ? 0 : T;
    u32* offi = offC + (size_t)img * NBT * NCH;
    u32* bti = basetot + (size_t)img * NBT;
    u32 cum = excl;
    int hi = NBT - 1 - tid * 8;
#pragma unroll
    for (int j = 0; j < 8; ++j) {
        int bin = hi - j;
        u32 c0 = reg[7 - j];
        if (bin > T) {
            u32 run = cum;
            for (int c = 0; c < NCH; ++c) {
                offi[(size_t)(bin - TT) * NCH + c] = run;
                run += Mi[(size_t)c * NBT + bin];
            }
            bti[bin] = (cum << 16) | c0;
        } else if (bin == T && T >= 0) {
            u32 run = TOPK;
            for (int c = 0; c < NCH; ++c) {
                offi[(size_t)(bin - TT) * NCH + c] = run;
                run += Mi[(size_t)c * NBT + bin];
            }
        }
        cum += c0;
    }
    u64* gk = gkeys + (size_t)img * GK;
    for (int i = tid; i < TOPK; i += 1024) gk[i] = 0ull;
    if (tid == 0) {
        tinfo[3 * img] = T;
        tinfo[3 * img + 1] = (int)sh_r;
        tinfo[3 * img + 2] = (int)sh_m;
    }
}

// ===== scatter: preload only R = NBT-TT compact offsets =====
__global__ __launch_bounds__(512) void k_scatter(const u64* __restrict__ surv,
                                                 const u32* __restrict__ cnt,
                                                 const int* __restrict__ tinfo,
                                                 const u32* __restrict__ offC,
                                                 u64* __restrict__ gkeys) {
    __shared__ u32 loff[NBT];
    int img = blockIdx.x / NCH, c = blockIdx.x % NCH;
    int tid = (int)threadIdx.x;
    int T = tinfo[3 * img];
    int TT = (T < 0) ? 0 : T;
    int R = NBT - TT;
    const u32* src = offC + (size_t)img * NBT * NCH;
    for (int i = tid; i < R; i += 512) loff[i] = src[(size_t)i * NCH + c];
    __syncthreads();
    u32 n = cnt[img];
    if (n > CAP) n = CAP;
    u32 chunk = (n + NCH - 1) / NCH;
    u32 lo = c * chunk, hiX = min(n, lo + chunk);
    const u64* sv = surv + (size_t)img * CAP;
    u64* gk = gkeys + (size_t)img * GK;
    for (u32 i = lo + tid; i < hiX; i += 512) {
        u64 kk = sv[i];
        int bb = binOf(kk);
        if (bb < TT) continue;
        u32 slot = atomicAdd(&loff[bb - TT], 1u);
        if (slot < GK) gk[slot] = kk;
    }
}

// ===== finalize: exact candidate ranks + within-segment ranks -> sorted =====
__global__ __launch_bounds__(1024) void k_fin(const int* __restrict__ tinfo,
                                              const u32* __restrict__ basetot,
                                              const u64* __restrict__ gkeys,
                                              u64* __restrict__ sorted) {
    __shared__ u64 up[TOPK];
    __shared__ u64 cnd[4096];
    int img = blockIdx.x, tid = (int)threadIdx.x;
    int T = tinfo[3 * img];
    u32 r = (u32)tinfo[3 * img + 1];
    u32 m = (u32)tinfo[3 * img + 2];
    if (m > 4096u) m = 4096u;
    const u64* gk = gkeys + (size_t)img * GK;
    for (int i = tid; i < TOPK; i += 1024) up[i] = gk[i];
    for (u32 i = tid; i < m; i += 1024) cnd[i] = gk[TOPK + i];
    __syncthreads();
    u64* dst = sorted + (size_t)img * TOPK;
    for (u32 i = tid; i < m; i += 1024) {
        u64 ki = cnd[i];
        u32 g = 0;
        for (u32 j = 0; j < m; ++j) g += (cnd[j] > ki) ? 1u : 0u;
        if (g < r) dst[TOPK - r + g] = ki;
    }
    u32 upper = TOPK - r;
    const u32* bti = basetot + (size_t)img * NBT;
    for (u32 s = tid; s < upper; s += 1024) {
        u64 kk = up[s];
        if (kk == 0ull) { dst[s] = 0ull; continue; }
        int bb = binOf(kk);
        u32 v = bti[bb];
        u32 base = v >> 16, cc = v & 0xFFFFu;
        u32 g = 0;
        for (u32 j = 0; j < cc; ++j) g += (up[base + j] > kk) ? 1u : 0u;
        dst[base + g] = kk;
    }
}

// ===== wave-parallel output: 2 keypoints/wave, 1 patch element/lane =====
__global__ __launch_bounds__(256) void k_out(const float* __restrict__ scores,
                                             const u64* __restrict__ sorted,
                                             float* __restrict__ out) {
    int gtid = blockIdx.x * 256 + (int)threadIdx.x;
    int wid = gtid >> 6;
    int l = gtid & 63;
    int half = l >> 5;
    int c = l & 31;
    int kpg = wid * 2 + half;
    int b = kpg >> 12;
    int kp = kpg & (TOPK - 1);
    const float* img = scores + (size_t)b * H * W;
    u64 key = sorted[(size_t)b * TOPK + kp];
    u32 idx = ~(u32)(key & 0xFFFFFFFFull);
    int ky = (int)(idx >> 10) & 1023, kx = (int)(idx & 1023);
    ky = min(max(ky, 2), H - 3);
    kx = min(max(kx, 2), W - 3);
    int row = c / 5, col = c % 5;
    float v = 0.0f;
    if (c < 25) v = img[(ky + row - 2) * W + (kx + col - 2)];
    float mx = (c < 25) ? v : -INFINITY;
#pragma unroll
    for (int mk = 1; mk < 32; mk <<= 1) mx = fmaxf(mx, __shfl_xor(mx, mk));
    float e = (c < 25) ? expf((v - mx) / 0.1f) : 0.0f;
    float dxv = (float)(col - 2), dyv = (float)(row - 2);
    float s0 = e, s1 = e * dxv, s2 = e * dyv;
#pragma unroll
    for (int mk = 1; mk < 32; mk <<= 1) {
        s0 += __shfl_xor(s0, mk);
        s1 += __shfl_xor(s1, mk);
        s2 += __shfl_xor(s2, mk);
    }
    float xr = s1 / s0, yr = s2 / s0;
    float ddx = (dxv - xr) * 0.5f, ddy = (dyv - yr) * 0.5f;
    float d = e * (ddx * ddx + ddy * ddy);
#pragma unroll
    for (int mk = 1; mk < 32; mk <<= 1) d += __shfl_xor(d, mk);
    float disp = d / s0;
    float kpx = ((float)kx + xr) / 1023.0f * 2.0f - 1.0f;
    float kpy = ((float)ky + yr) / 1023.0f * 2.0f - 1.0f;
    float px = (kpx + 1.0f) * 0.5f * 1023.0f;
    float py = (kpy + 1.0f) * 0.5f * 1023.0f;
    float fx = floorf(px), fy = floorf(py);
    float wx = px - fx, wy = py - fy;
    int x0 = (int)fminf(fmaxf(fx, 0.f), 1023.f);
    int x1 = (int)fminf(fmaxf(fx + 1.f, 0.f), 1023.f);
    int y0 = (int)fminf(fmaxf(fy, 0.f), 1023.f);
    int y1 = (int)fminf(fmaxf(fy + 1.f, 0.f), 1023.f);
    float bv = 0.0f;
    if (c < 4) {
        int xx = (c & 1) ? x1 : x0;
        int yy = (c >> 1) ? y1 : y0;
        bv = img[yy * W + xx];
    }
    int base = half * 32;
    float v00 = __shfl(bv, base + 0);
    float v01 = __shfl(bv, base + 1);
    float v10 = __shfl(bv, base + 2);
    float v11 = __shfl(bv, base + 3);
    float sc = v00 * (1.f - wx) * (1.f - wy) + v01 * wx * (1.f - wy) +
               v10 * (1.f - wx) * wy + v11 * wx * wy;
    if (c == 0) {
        size_t kb = (size_t)b * TOPK + kp;
        out[kb * 2 + 0] = kpx;
        out[kb * 2 + 1] = kpy;
        out[(size_t)B * TOPK * 2 + kb] = disp;
        out[(size_t)B * TOPK * 3 + kb] = sc;
    }
}

extern "C" void kernel_launch(void* const* d_in, const int* in_sizes, int n_in,
                              void* d_out, int out_size, void* d_ws, size_t ws_size,
                              hipStream_t stream) {
    const float* scores = (const float*)d_in[0];
    float* out = (float*)d_out;
    char* ws = (char*)d_ws;
    u64* surv = (u64*)ws;                                   // 8 MB
    u16* M = (u16*)(ws + 8388608);                          // 2 MB (u16, NCH=16)
    u32* offC = (u32*)(ws + 10485760);                      // 4 MB (compact-indexed)
    u32* basetot = (u32*)(ws + 14680064);                   // 256 KB
    u64* gkeys = (u64*)(ws + 15204352);                     // 1.31 MB
    u64* sorted = (u64*)(ws + 16515072);                    // 256 KB
    u32* cnt = (u32*)(ws + 16777216);                       // 32 B
    int* tinfo = (int*)(ws + 16777280);                     // 96 B

    hipMemsetAsync(cnt, 0, B * sizeof(u32), stream);

    k_nms<<<dim3(GDX, GDY, B), 512, 0, stream>>>(scores, surv, cnt);
    k_hist<<<B * NCH, 512, 0, stream>>>(surv, cnt, M);
    k_scan<<<B, 1024, 0, stream>>>(M, offC, basetot, tinfo, gkeys);
    k_scatter<<<B * NCH, 512, 0, stream>>>(surv, cnt, tinfo, offC, gkeys);
    k_fin<<<B, 1024, 0, stream>>>(tinfo, basetot, gkeys, sorted);
    k_out<<<(B * TOPK * 32) / 256, 256, 0, stream>>>(scores, sorted, out);
}

// Round 26
// 102.826 us; speedup vs baseline: 1.1535x; 1.0289x over previous
//
#include <hip/hip_runtime.h>
#include <math.h>

#define H 1024
#define W 1024
#define B 8
#define TOPK 4096
#define CAP 131072
#define NBT 8192
#define NCH 16
#define GK 20480
#define TILE_X 108
#define TILE_Y 108
#define GDX 10
#define GDY 10
#define SKCAP 2048

typedef unsigned long long u64;
typedef unsigned int u32;
typedef unsigned short u16;

// DPP lane shifts (VALU, no DS). wave_shr1 (0x138) == shfl_up(v,1);
// wave_shl1 (0x130) == shfl_down(v,1). bound_ctrl zero-fill at lanes 0/63 is
// harmless: those lanes own region cols {0,1}/{126,127}, excluded by extents.
__device__ __forceinline__ float dpp_up1(float v) {
    int r = __builtin_amdgcn_update_dpp(0, __float_as_int(v), 0x138, 0xF, 0xF, true);
    return __int_as_float(r);
}
__device__ __forceinline__ float dpp_dn1(float v) {
    int r = __builtin_amdgcn_update_dpp(0, __float_as_int(v), 0x130, 0xF, 0xF, true);
    return __int_as_float(r);
}

// Monotone bin index, fine-grained where survivor values cluster (v in [0.5,1)).
__device__ __forceinline__ int binOf(u64 key) {
    u32 fb = (u32)(key >> 32);
    u32 ex = fb >> 23;
    if (ex >= 0x7Fu) return NBT - 1;
    if (ex == 0x7Eu) {
        u32 m13 = (fb >> 10) & 0x1FFFu;
        return (m13 < 64u) ? 64 : (int)m13;
    }
    if (ex >= 0x6Eu) return (int)(ex - 0x6Eu + 47u);
    return 1;
}

// ================= Fused 3-round NMS + survivor compaction (round-24 verbatim) =================
#define ROUND_A(VR0, VR1, USE_SUPP)                                               \
    _Pragma("unroll") for (int i = 0; i < 16; ++i) {                              \
        int r = rbase + i;                                                        \
        if (r < (VR0) || r > (VR1)) continue;                                     \
        float x = svx[i], y = svy[i];                                             \
        if (USE_SUPP) {                                                           \
            u64 se = sp[r][0], so = sp[r][1];                                     \
            u32 s0 = (u32)(se >> lane) & 1u;                                      \
            u32 s1 = (u32)(so >> lane) & 1u;                                      \
            sbx |= s0 << i;                                                       \
            sby |= s1 << i;                                                       \
            if (s0) x = 0.0f;                                                     \
            if (s1) y = 0.0f;                                                     \
        }                                                                         \
        float ux = dpp_up1(x), uy = dpp_up1(y);                                   \
        float dxx = dpp_dn1(x), dyy = dpp_dn1(y);                                 \
        float m01 = fmaxf(x, y);                                                  \
        float h0 = fmaxf(fmaxf(ux, uy), fmaxf(m01, dxx));                         \
        float h1 = fmaxf(fmaxf(uy, m01), fmaxf(dxx, dyy));                        \
        h0r[i] = h0;                                                              \
        h1r[i] = h1;                                                              \
        if (i == 0 || i == 1 || i == 14 || i == 15) {                             \
            int k = (i < 2) ? i : i - 12;                                         \
            *(float2*)&hb[w * 4 + k][2 * lane] = make_float2(h0, h1);             \
        }                                                                         \
    }

#define GATHER_V()                                                                \
        float v0x, v0y, v1x, v1y, v3x, v3y, v4x, v4y;                             \
        if (i >= 2) { v0x = h0r[i - 2]; v0y = h1r[i - 2]; }                       \
        else { int k = (i == 0) ? 2 : 3;                                          \
               float2 t = *(const float2*)&hb[(w - 1) * 4 + k][2 * lane];         \
               v0x = t.x; v0y = t.y; }                                            \
        if (i >= 1) { v1x = h0r[i - 1]; v1y = h1r[i - 1]; }                       \
        else { float2 t = *(const float2*)&hb[(w - 1) * 4 + 3][2 * lane];         \
               v1x = t.x; v1y = t.y; }                                            \
        if (i <= 14) { v3x = h0r[i + 1]; v3y = h1r[i + 1]; }                      \
        else { float2 t = *(const float2*)&hb[(w + 1) * 4 + 0][2 * lane];         \
               v3x = t.x; v3y = t.y; }                                            \
        if (i <= 13) { v4x = h0r[i + 2]; v4y = h1r[i + 2]; }                      \
        else { int k = (i == 14) ? 0 : 1;                                         \
               float2 t = *(const float2*)&hb[(w + 1) * 4 + k][2 * lane];         \
               v4x = t.x; v4y = t.y; }

#define ROUND_B(VV0, VV1, USE_SUPP, FIRST)                                        \
    _Pragma("unroll") for (int i = 0; i < 16; ++i) {                              \
        int r = rbase + i;                                                        \
        if (r < (VV0) || r > (VV1)) continue;                                     \
        GATHER_V()                                                                \
        float vm0 = fmaxf(fmaxf(fmaxf(v0x, v1x), fmaxf(v3x, v4x)), h0r[i]);       \
        float vm1 = fmaxf(fmaxf(fmaxf(v0y, v1y), fmaxf(v3y, v4y)), h1r[i]);       \
        float x = svx[i], y = svy[i];                                             \
        bool sb0 = false, sb1 = false;                                            \
        if (USE_SUPP) {                                                           \
            sb0 = (sbx >> i) & 1u;                                                \
            sb1 = (sby >> i) & 1u;                                                \
            if (sb0) x = 0.0f;                                                    \
            if (sb1) y = 0.0f;                                                    \
        }                                                                         \
        int c0 = 2 * lane;                                                        \
        bool bit0 = (x == vm0) && !sb0 && (svx[i] != -INFINITY) &&                \
                    c0 >= (VV0) && c0 <= (VV1);                                   \
        bool bit1 = (y == vm1) && !sb1 && (svy[i] != -INFINITY) &&                \
                    (c0 + 1) >= (VV0) && (c0 + 1) <= (VV1);                       \
        u64 bE = __ballot(bit0), bO = __ballot(bit1);                             \
        if (lane == 0) {                                                          \
            u64 ne = ((FIRST) ? 0ull : ma[r][0]) | bE;                            \
            u64 no = ((FIRST) ? 0ull : ma[r][1]) | bO;                            \
            ma[r][0] = ne;                                                        \
            ma[r][1] = no;                                                        \
        }                                                                         \
    }

#define ROUND_B_FINAL()                                                           \
    _Pragma("unroll") for (int i = 0; i < 16; ++i) {                              \
        int r = rbase + i;                                                        \
        if (r < 10 || r > 117) continue;                                          \
        GATHER_V()                                                                \
        float vm0 = fmaxf(fmaxf(fmaxf(v0x, v1x), fmaxf(v3x, v4x)), h0r[i]);       \
        float vm1 = fmaxf(fmaxf(fmaxf(v0y, v1y), fmaxf(v3y, v4y)), h1r[i]);       \
        float x = svx[i], y = svy[i];                                             \
        bool sb0 = (sbx >> i) & 1u;                                               \
        bool sb1 = (sby >> i) & 1u;                                               \
        if (sb0) x = 0.0f;                                                        \
        if (sb1) y = 0.0f;                                                        \
        int c0 = 2 * lane;                                                        \
        bool bit0 = (x == vm0) && !sb0 && (svx[i] != -INFINITY);                  \
        bool bit1 = (y == vm1) && !sb1 && (svy[i] != -INFINITY);                  \
        u64 me_old = ma[r][0], mo_old = ma[r][1];                                 \
        bool fin0 = bit0 || (((me_old >> lane) & 1ull) != 0);                     \
        bool fin1 = bit1 || (((mo_old >> lane) & 1ull) != 0);                     \
        int gy = gy0 + r;                                                         \
        if (c0 >= 10 && c0 <= 117 && fin0 && svx[i] > 0.0f &&                     \
            gx >= 2 && gx < W - 2 && gy >= 2 && gy < H - 2) {                     \
            u32 pos = atomicAdd(&lcnt, 1u);                                       \
            if (pos < SKCAP) {                                                    \
                u32 p = (u32)(gy * W + gx);                                       \
                skey[pos] = ((u64)__float_as_uint(svx[i]) << 32) | (u64)(~p);     \
            }                                                                     \
        }                                                                         \
        if (c0 + 1 >= 10 && c0 + 1 <= 117 && fin1 && svy[i] > 0.0f &&             \
            gx + 1 >= 2 && gx + 1 < W - 2 && gy >= 2 && gy < H - 2) {             \
            u32 pos = atomicAdd(&lcnt, 1u);                                       \
            if (pos < SKCAP) {                                                    \
                u32 p = (u32)(gy * W + gx + 1);                                   \
                skey[pos] = ((u64)__float_as_uint(svy[i]) << 32) | (u64)(~p);     \
            }                                                                     \
        }                                                                         \
    }

#define DILATE(R0, R1)                                                            \
    if (tid >= (R0) && tid <= (R1)) {                                             \
        int rr = tid;                                                             \
        u64 e = ma[rr - 2][0] | ma[rr - 1][0] | ma[rr][0] | ma[rr + 1][0] |       \
                ma[rr + 2][0];                                                    \
        u64 o = ma[rr - 2][1] | ma[rr - 1][1] | ma[rr][1] | ma[rr + 1][1] |       \
                ma[rr + 2][1];                                                    \
        sp[rr][0] = e | (e << 1) | (e >> 1) | o | (o << 1);                       \
        sp[rr][1] = o | (o << 1) | (o >> 1) | e | (e >> 1);                       \
    }

__global__ __launch_bounds__(512) void k_nms(const float* __restrict__ scores,
                                             u64* __restrict__ surv,
                                             u32* __restrict__ cnt) {
    __shared__ float hb[32][128];                  // 16 KB
    __shared__ __align__(16) u64 ma[128][2];       // [E,O] interleaved
    __shared__ __align__(16) u64 sp[128][2];
    __shared__ u64 skey[SKCAP];                    // 16 KB (separate; hb live)
    __shared__ u32 lcnt, gbase;
    const int b = blockIdx.z;
    const int gx0 = blockIdx.x * TILE_X - 10;
    const int gy0 = blockIdx.y * TILE_Y - 10;
    const float* img = scores + (size_t)b * H * W;
    const int tid = (int)threadIdx.x, lane = tid & 63, w = tid >> 6, rbase = w * 16;
    const int gx = gx0 + 2 * lane;
    if (tid == 0) lcnt = 0;

    float svx[16], svy[16], h0r[16], h1r[16];
    u32 sbx = 0, sby = 0;
#pragma unroll
    for (int i = 0; i < 16; ++i) {
        int gy = gy0 + rbase + i;
        float x = -INFINITY, y = -INFINITY;
        if (gy >= 0 && gy < H) {
            const float* row = img + (size_t)gy * W;
            if (gx >= 0 && gx + 1 < W) {
                float2 t = *(const float2*)(row + gx);
                x = t.x; y = t.y;
            } else if (gx >= 0 && gx < W) {
                x = row[gx];
            }
        }
        svx[i] = x; svy[i] = y;
    }

    ROUND_A(0, 127, false)
    __syncthreads();
    ROUND_B(2, 125, false, 1)
    __syncthreads();
    DILATE(4, 123)
    __syncthreads();
    sbx = 0; sby = 0;
    ROUND_A(4, 123, true)
    __syncthreads();
    ROUND_B(6, 121, true, 0)
    __syncthreads();
    DILATE(8, 119)
    __syncthreads();
    sbx = 0; sby = 0;
    ROUND_A(8, 119, true)
    __syncthreads();
    ROUND_B_FINAL()
    __syncthreads();
    u32 nk = lcnt < SKCAP ? lcnt : SKCAP;
    if (tid == 0) gbase = nk ? atomicAdd(&cnt[b], nk) : 0u;
    __syncthreads();
    for (u32 i = tid; i < nk; i += 512)
        surv[(size_t)b * CAP + gbase + i] = skey[i];
}

// ===== per-chunk private histograms; M (u16) layout [img][chunk][bin] =====
__global__ __launch_bounds__(512) void k_hist(const u64* __restrict__ surv,
                                              const u32* __restrict__ cnt,
                                              u16* __restrict__ M) {
    __shared__ u32 h[NBT];
    int img = blockIdx.x / NCH, c = blockIdx.x % NCH;
    int tid = (int)threadIdx.x;
    for (int i = tid; i < NBT; i += 512) h[i] = 0;
    __syncthreads();
    u32 n = cnt[img];
    if (n > CAP) n = CAP;
    u32 chunk = (n + NCH - 1) / NCH;
    u32 lo = c * chunk, hi = min(n, lo + chunk);
    const u64* sv = surv + (size_t)img * CAP;
    for (u32 i = lo + tid; i < hi; i += 512) atomicAdd(&h[binOf(sv[i])], 1u);
    __syncthreads();
    u16* dst = M + ((size_t)img * NCH + c) * NBT;
    for (int i = tid; i < NBT; i += 512) dst[i] = (u16)h[i];
}

// ===== scan: register accumulate (ushort4 loads) + shuffle scan =====
__global__ __launch_bounds__(1024) void k_scan(const u16* __restrict__ M,
                                               u32* __restrict__ offC,
                                               u32* __restrict__ basetot,
                                               int* __restrict__ tinfo,
                                               u64* __restrict__ gkeys) {
    __shared__ u32 wsum[16];
    __shared__ u32 sh_ntot;
    __shared__ int sh_T;
    __shared__ u32 sh_r, sh_m;
    int img = blockIdx.x, tid = (int)threadIdx.x;
    const u16* Mi = M + (size_t)img * NCH * NBT;
    const int base = NBT - 8 - tid * 8;
    u32 reg[8] = {0, 0, 0, 0, 0, 0, 0, 0};
    for (int c = 0; c < NCH; ++c) {
        const u16* p = Mi + (size_t)c * NBT + base;
        ushort4 a = *(const ushort4*)(p);
        ushort4 b2 = *(const ushort4*)(p + 4);
        reg[0] += a.x; reg[1] += a.y; reg[2] += a.z; reg[3] += a.w;
        reg[4] += b2.x; reg[5] += b2.y; reg[6] += b2.z; reg[7] += b2.w;
    }
    u32 tot = 0;
#pragma unroll
    for (int j = 0; j < 8; ++j) tot += reg[j];
    u32 x = tot;
    int ln = tid & 63, wv = tid >> 6;
#pragma unroll
    for (int off = 1; off < 64; off <<= 1) {
        u32 v = (u32)__shfl_up((int)x, off);
        if (ln >= off) x += v;
    }
    if (ln == 63) wsum[wv] = x;
    __syncthreads();
    if (tid < 16) {
        u32 wval = wsum[tid];
        u32 wx = wval;
        for (int off = 1; off < 16; off <<= 1) {
            u32 v = (u32)__shfl_up((int)wx, off);
            if (tid >= off) wx += v;
        }
        wsum[tid] = wx - wval;
        if (tid == 15) sh_ntot = wx;
    }
    __syncthreads();
    u32 incl = x + wsum[wv];
    u32 excl = incl - tot;
    u32 ntot = sh_ntot;
    if (ntot > TOPK) {
        if (excl < TOPK && TOPK <= incl) {
            u32 cum = excl;
#pragma unroll
            for (int j = 0; j < 8; ++j) {
                u32 cj = reg[7 - j];
                if (cum + cj >= TOPK) {
                    sh_T = NBT - 1 - tid * 8 - j;
                    sh_r = TOPK - cum;
                    sh_m = cj;
                    break;
                }
                cum += cj;
            }
        }
    } else if (tid == 0) { sh_T = -1; sh_r = 0; sh_m = 0; }
    __syncthreads();
    int T = sh_T;
    int TT = (T < 0) ? 0 : T;
    u32* offi = offC + (size_t)img * NBT * NCH;
    u32* bti = basetot + (size_t)img * NBT;
    u32 cum = excl;
    int hi = NBT - 1 - tid * 8;
#pragma unroll
    for (int j = 0; j < 8; ++j) {
        int bin = hi - j;
        u32 c0 = reg[7 - j];
        if (bin > T) {
            u32 run = cum;
            for (int c = 0; c < NCH; ++c) {
                offi[(size_t)(bin - TT) * NCH + c] = run;
                run += Mi[(size_t)c * NBT + bin];
            }
            bti[bin] = (cum << 16) | c0;
        } else if (bin == T && T >= 0) {
            u32 run = TOPK;
            for (int c = 0; c < NCH; ++c) {
                offi[(size_t)(bin - TT) * NCH + c] = run;
                run += Mi[(size_t)c * NBT + bin];
            }
        }
        cum += c0;
    }
    u64* gk = gkeys + (size_t)img * GK;
    for (int i = tid; i < TOPK; i += 1024) gk[i] = 0ull;
    if (tid == 0) {
        tinfo[3 * img] = T;
        tinfo[3 * img + 1] = (int)sh_r;
        tinfo[3 * img + 2] = (int)sh_m;
    }
}

// ===== scatter: preload only R = NBT-TT compact offsets =====
__global__ __launch_bounds__(512) void k_scatter(const u64* __restrict__ surv,
                                                 const u32* __restrict__ cnt,
                                                 const int* __restrict__ tinfo,
                                                 const u32* __restrict__ offC,
                                                 u64* __restrict__ gkeys) {
    __shared__ u32 loff[NBT];
    int img = blockIdx.x / NCH, c = blockIdx.x % NCH;
    int tid = (int)threadIdx.x;
    int T = tinfo[3 * img];
    int TT = (T < 0) ? 0 : T;
    int R = NBT - TT;
    const u32* src = offC + (size_t)img * NBT * NCH;
    for (int i = tid; i < R; i += 512) loff[i] = src[(size_t)i * NCH + c];
    __syncthreads();
    u32 n = cnt[img];
    if (n > CAP) n = CAP;
    u32 chunk = (n + NCH - 1) / NCH;
    u32 lo = c * chunk, hiX = min(n, lo + chunk);
    const u64* sv = surv + (size_t)img * CAP;
    u64* gk = gkeys + (size_t)img * GK;
    for (u32 i = lo + tid; i < hiX; i += 512) {
        u64 kk = sv[i];
        int bb = binOf(kk);
        if (bb < TT) continue;
        u32 slot = atomicAdd(&loff[bb - TT], 1u);
        if (slot < GK) gk[slot] = kk;
    }
}

// ===== finalize v2: 17 blocks/image, global reads (L2-hot), no LDS staging =====
// Slices 0..15: one thread per upper slot; exact rank within its bin segment.
// Slice 16: threshold-bin candidates -> slots [TOPK-r, TOPK).
__global__ __launch_bounds__(256) void k_fin(const int* __restrict__ tinfo,
                                             const u32* __restrict__ basetot,
                                             const u64* __restrict__ gkeys,
                                             u64* __restrict__ sorted) {
    int img = blockIdx.x / 17;
    int slice = blockIdx.x % 17;
    int tid = (int)threadIdx.x;
    int T = tinfo[3 * img];
    u32 r = (u32)tinfo[3 * img + 1];
    u32 m = (u32)tinfo[3 * img + 2];
    if (m > (u32)(GK - TOPK)) m = (u32)(GK - TOPK);
    const u64* gk = gkeys + (size_t)img * GK;
    const u32* bti = basetot + (size_t)img * NBT;
    u64* dst = sorted + (size_t)img * TOPK;
    if (slice < 16) {
        u32 s = (u32)(slice * 256 + tid);
        u32 upper = TOPK - r;
        if (s < upper) {
            u64 kk = gk[s];
            if (kk == 0ull) {
                dst[s] = 0ull;
            } else {
                int bb = binOf(kk);
                u32 v = bti[bb];
                u32 base = v >> 16, cc = v & 0xFFFFu;
                u32 g = 0;
                for (u32 j = 0; j < cc; ++j) g += (gk[base + j] > kk) ? 1u : 0u;
                dst[base + g] = kk;
            }
        }
    } else {
        for (u32 i = (u32)tid; i < m; i += 256) {
            u64 ki = gk[TOPK + i];
            u32 g = 0;
            for (u32 j = 0; j < m; ++j) g += (gk[TOPK + j] > ki) ? 1u : 0u;
            if (g < r) dst[TOPK - r + g] = ki;
        }
    }
}

// ===== wave-parallel output: 2 keypoints/wave, 1 patch element/lane =====
__global__ __launch_bounds__(256) void k_out(const float* __restrict__ scores,
                                             const u64* __restrict__ sorted,
                                             float* __restrict__ out) {
    int gtid = blockIdx.x * 256 + (int)threadIdx.x;
    int wid = gtid >> 6;
    int l = gtid & 63;
    int half = l >> 5;
    int c = l & 31;
    int kpg = wid * 2 + half;
    int b = kpg >> 12;
    int kp = kpg & (TOPK - 1);
    const float* img = scores + (size_t)b * H * W;
    u64 key = sorted[(size_t)b * TOPK + kp];
    u32 idx = ~(u32)(key & 0xFFFFFFFFull);
    int ky = (int)(idx >> 10) & 1023, kx = (int)(idx & 1023);
    ky = min(max(ky, 2), H - 3);
    kx = min(max(kx, 2), W - 3);
    int row = c / 5, col = c % 5;
    float v = 0.0f;
    if (c < 25) v = img[(ky + row - 2) * W + (kx + col - 2)];
    float mx = (c < 25) ? v : -INFINITY;
#pragma unroll
    for (int mk = 1; mk < 32; mk <<= 1) mx = fmaxf(mx, __shfl_xor(mx, mk));
    float e = (c < 25) ? expf((v - mx) / 0.1f) : 0.0f;
    float dxv = (float)(col - 2), dyv = (float)(row - 2);
    float s0 = e, s1 = e * dxv, s2 = e * dyv;
#pragma unroll
    for (int mk = 1; mk < 32; mk <<= 1) {
        s0 += __shfl_xor(s0, mk);
        s1 += __shfl_xor(s1, mk);
        s2 += __shfl_xor(s2, mk);
    }
    float xr = s1 / s0, yr = s2 / s0;
    float ddx = (dxv - xr) * 0.5f, ddy = (dyv - yr) * 0.5f;
    float d = e * (ddx * ddx + ddy * ddy);
#pragma unroll
    for (int mk = 1; mk < 32; mk <<= 1) d += __shfl_xor(d, mk);
    float disp = d / s0;
    float kpx = ((float)kx + xr) / 1023.0f * 2.0f - 1.0f;
    float kpy = ((float)ky + yr) / 1023.0f * 2.0f - 1.0f;
    float px = (kpx + 1.0f) * 0.5f * 1023.0f;
    float py = (kpy + 1.0f) * 0.5f * 1023.0f;
    float fx = floorf(px), fy = floorf(py);
    float wx = px - fx, wy = py - fy;
    int x0 = (int)fminf(fmaxf(fx, 0.f), 1023.f);
    int x1 = (int)fminf(fmaxf(fx + 1.f, 0.f), 1023.f);
    int y0 = (int)fminf(fmaxf(fy, 0.f), 1023.f);
    int y1 = (int)fminf(fmaxf(fy + 1.f, 0.f), 1023.f);
    float bv = 0.0f;
    if (c < 4) {
        int xx = (c & 1) ? x1 : x0;
        int yy = (c >> 1) ? y1 : y0;
        bv = img[yy * W + xx];
    }
    int base = half * 32;
    float v00 = __shfl(bv, base + 0);
    float v01 = __shfl(bv, base + 1);
    float v10 = __shfl(bv, base + 2);
    float v11 = __shfl(bv, base + 3);
    float sc = v00 * (1.f - wx) * (1.f - wy) + v01 * wx * (1.f - wy) +
               v10 * (1.f - wx) * wy + v11 * wx * wy;
    if (c == 0) {
        size_t kb = (size_t)b * TOPK + kp;
        out[kb * 2 + 0] = kpx;
        out[kb * 2 + 1] = kpy;
        out[(size_t)B * TOPK * 2 + kb] = disp;
        out[(size_t)B * TOPK * 3 + kb] = sc;
    }
}

extern "C" void kernel_launch(void* const* d_in, const int* in_sizes, int n_in,
                              void* d_out, int out_size, void* d_ws, size_t ws_size,
                              hipStream_t stream) {
    const float* scores = (const float*)d_in[0];
    float* out = (float*)d_out;
    char* ws = (char*)d_ws;
    u64* surv = (u64*)ws;                                   // 8 MB
    u16* M = (u16*)(ws + 8388608);                          // 2 MB (u16, NCH=16)
    u32* offC = (u32*)(ws + 10485760);                      // 4 MB (compact-indexed)
    u32* basetot = (u32*)(ws + 14680064);                   // 256 KB
    u64* gkeys = (u64*)(ws + 15204352);                     // 1.31 MB
    u64* sorted = (u64*)(ws + 16515072);                    // 256 KB
    u32* cnt = (u32*)(ws + 16777216);                       // 32 B
    int* tinfo = (int*)(ws + 16777280);                     // 96 B

    hipMemsetAsync(cnt, 0, B * sizeof(u32), stream);

    k_nms<<<dim3(GDX, GDY, B), 512, 0, stream>>>(scores, surv, cnt);
    k_hist<<<B * NCH, 512, 0, stream>>>(surv, cnt, M);
    k_scan<<<B, 1024, 0, stream>>>(M, offC, basetot, tinfo, gkeys);
    k_scatter<<<B * NCH, 512, 0, stream>>>(surv, cnt, tinfo, offC, gkeys);
    k_fin<<<B * 17, 256, 0, stream>>>(tinfo, basetot, gkeys, sorted);
    k_out<<<(B * TOPK * 32) / 256, 256, 0, stream>>>(scores, sorted, out);
}

// Round 27
// 102.063 us; speedup vs baseline: 1.1621x; 1.0075x over previous
//
#include <hip/hip_runtime.h>
#include <math.h>

#define H 1024
#define W 1024
#define B 8
#define TOPK 4096
#define CAP 131072
#define NBT 8192
#define NCH 16
#define GK 20480
#define TILE_X 108
#define TILE_Y 108
#define GDX 10
#define GDY 10
#define SKCAP 2048

typedef unsigned long long u64;
typedef unsigned int u32;
typedef unsigned short u16;

// DPP lane shifts (VALU, no DS). wave_shr1 (0x138) == shfl_up(v,1);
// wave_shl1 (0x130) == shfl_down(v,1). bound_ctrl zero-fill at lanes 0/63 is
// harmless: those lanes own region cols {0,1}/{126,127}, excluded by extents.
__device__ __forceinline__ float dpp_up1(float v) {
    int r = __builtin_amdgcn_update_dpp(0, __float_as_int(v), 0x138, 0xF, 0xF, true);
    return __int_as_float(r);
}
__device__ __forceinline__ float dpp_dn1(float v) {
    int r = __builtin_amdgcn_update_dpp(0, __float_as_int(v), 0x130, 0xF, 0xF, true);
    return __int_as_float(r);
}

// Monotone bin index, fine-grained where survivor values cluster (v in [0.5,1)).
__device__ __forceinline__ int binOf(u64 key) {
    u32 fb = (u32)(key >> 32);
    u32 ex = fb >> 23;
    if (ex >= 0x7Fu) return NBT - 1;
    if (ex == 0x7Eu) {
        u32 m13 = (fb >> 10) & 0x1FFFu;
        return (m13 < 64u) ? 64 : (int)m13;
    }
    if (ex >= 0x6Eu) return (int)(ex - 0x6Eu + 47u);
    return 1;
}

// ================= Fused 3-round NMS + survivor compaction (round-24 verbatim) =================
#define ROUND_A(VR0, VR1, USE_SUPP)                                               \
    _Pragma("unroll") for (int i = 0; i < 16; ++i) {                              \
        int r = rbase + i;                                                        \
        if (r < (VR0) || r > (VR1)) continue;                                     \
        float x = svx[i], y = svy[i];                                             \
        if (USE_SUPP) {                                                           \
            u64 se = sp[r][0], so = sp[r][1];                                     \
            u32 s0 = (u32)(se >> lane) & 1u;                                      \
            u32 s1 = (u32)(so >> lane) & 1u;                                      \
            sbx |= s0 << i;                                                       \
            sby |= s1 << i;                                                       \
            if (s0) x = 0.0f;                                                     \
            if (s1) y = 0.0f;                                                     \
        }                                                                         \
        float ux = dpp_up1(x), uy = dpp_up1(y);                                   \
        float dxx = dpp_dn1(x), dyy = dpp_dn1(y);                                 \
        float m01 = fmaxf(x, y);                                                  \
        float h0 = fmaxf(fmaxf(ux, uy), fmaxf(m01, dxx));                         \
        float h1 = fmaxf(fmaxf(uy, m01), fmaxf(dxx, dyy));                        \
        h0r[i] = h0;                                                              \
        h1r[i] = h1;                                                              \
        if (i == 0 || i == 1 || i == 14 || i == 15) {                             \
            int k = (i < 2) ? i : i - 12;                                         \
            *(float2*)&hb[w * 4 + k][2 * lane] = make_float2(h0, h1);             \
        }                                                                         \
    }

#define GATHER_V()                                                                \
        float v0x, v0y, v1x, v1y, v3x, v3y, v4x, v4y;                             \
        if (i >= 2) { v0x = h0r[i - 2]; v0y = h1r[i - 2]; }                       \
        else { int k = (i == 0) ? 2 : 3;                                          \
               float2 t = *(const float2*)&hb[(w - 1) * 4 + k][2 * lane];         \
               v0x = t.x; v0y = t.y; }                                            \
        if (i >= 1) { v1x = h0r[i - 1]; v1y = h1r[i - 1]; }                       \
        else { float2 t = *(const float2*)&hb[(w - 1) * 4 + 3][2 * lane];         \
               v1x = t.x; v1y = t.y; }                                            \
        if (i <= 14) { v3x = h0r[i + 1]; v3y = h1r[i + 1]; }                      \
        else { float2 t = *(const float2*)&hb[(w + 1) * 4 + 0][2 * lane];         \
               v3x = t.x; v3y = t.y; }                                            \
        if (i <= 13) { v4x = h0r[i + 2]; v4y = h1r[i + 2]; }                      \
        else { int k = (i == 14) ? 0 : 1;                                         \
               float2 t = *(const float2*)&hb[(w + 1) * 4 + k][2 * lane];         \
               v4x = t.x; v4y = t.y; }

#define ROUND_B(VV0, VV1, USE_SUPP, FIRST)                                        \
    _Pragma("unroll") for (int i = 0; i < 16; ++i) {                              \
        int r = rbase + i;                                                        \
        if (r < (VV0) || r > (VV1)) continue;                                     \
        GATHER_V()                                                                \
        float vm0 = fmaxf(fmaxf(fmaxf(v0x, v1x), fmaxf(v3x, v4x)), h0r[i]);       \
        float vm1 = fmaxf(fmaxf(fmaxf(v0y, v1y), fmaxf(v3y, v4y)), h1r[i]);       \
        float x = svx[i], y = svy[i];                                             \
        bool sb0 = false, sb1 = false;                                            \
        if (USE_SUPP) {                                                           \
            sb0 = (sbx >> i) & 1u;                                                \
            sb1 = (sby >> i) & 1u;                                                \
            if (sb0) x = 0.0f;                                                    \
            if (sb1) y = 0.0f;                                                    \
        }                                                                         \
        int c0 = 2 * lane;                                                        \
        bool bit0 = (x == vm0) && !sb0 && (svx[i] != -INFINITY) &&                \
                    c0 >= (VV0) && c0 <= (VV1);                                   \
        bool bit1 = (y == vm1) && !sb1 && (svy[i] != -INFINITY) &&                \
                    (c0 + 1) >= (VV0) && (c0 + 1) <= (VV1);                       \
        u64 bE = __ballot(bit0), bO = __ballot(bit1);                             \
        if (lane == 0) {                                                          \
            u64 ne = ((FIRST) ? 0ull : ma[r][0]) | bE;                            \
            u64 no = ((FIRST) ? 0ull : ma[r][1]) | bO;                            \
            ma[r][0] = ne;                                                        \
            ma[r][1] = no;                                                        \
        }                                                                         \
    }

#define ROUND_B_FINAL()                                                           \
    _Pragma("unroll") for (int i = 0; i < 16; ++i) {                              \
        int r = rbase + i;                                                        \
        if (r < 10 || r > 117) continue;                                          \
        GATHER_V()                                                                \
        float vm0 = fmaxf(fmaxf(fmaxf(v0x, v1x), fmaxf(v3x, v4x)), h0r[i]);       \
        float vm1 = fmaxf(fmaxf(fmaxf(v0y, v1y), fmaxf(v3y, v4y)), h1r[i]);       \
        float x = svx[i], y = svy[i];                                             \
        bool sb0 = (sbx >> i) & 1u;                                               \
        bool sb1 = (sby >> i) & 1u;                                               \
        if (sb0) x = 0.0f;                                                        \
        if (sb1) y = 0.0f;                                                        \
        int c0 = 2 * lane;                                                        \
        bool bit0 = (x == vm0) && !sb0 && (svx[i] != -INFINITY);                  \
        bool bit1 = (y == vm1) && !sb1 && (svy[i] != -INFINITY);                  \
        u64 me_old = ma[r][0], mo_old = ma[r][1];                                 \
        bool fin0 = bit0 || (((me_old >> lane) & 1ull) != 0);                     \
        bool fin1 = bit1 || (((mo_old >> lane) & 1ull) != 0);                     \
        int gy = gy0 + r;                                                         \
        if (c0 >= 10 && c0 <= 117 && fin0 && svx[i] > 0.0f &&                     \
            gx >= 2 && gx < W - 2 && gy >= 2 && gy < H - 2) {                     \
            u32 pos = atomicAdd(&lcnt, 1u);                                       \
            if (pos < SKCAP) {                                                    \
                u32 p = (u32)(gy * W + gx);                                       \
                skey[pos] = ((u64)__float_as_uint(svx[i]) << 32) | (u64)(~p);     \
            }                                                                     \
        }                                                                         \
        if (c0 + 1 >= 10 && c0 + 1 <= 117 && fin1 && svy[i] > 0.0f &&             \
            gx + 1 >= 2 && gx + 1 < W - 2 && gy >= 2 && gy < H - 2) {             \
            u32 pos = atomicAdd(&lcnt, 1u);                                       \
            if (pos < SKCAP) {                                                    \
                u32 p = (u32)(gy * W + gx + 1);                                   \
                skey[pos] = ((u64)__float_as_uint(svy[i]) << 32) | (u64)(~p);     \
            }                                                                     \
        }                                                                         \
    }

#define DILATE(R0, R1)                                                            \
    if (tid >= (R0) && tid <= (R1)) {                                             \
        int rr = tid;                                                             \
        u64 e = ma[rr - 2][0] | ma[rr - 1][0] | ma[rr][0] | ma[rr + 1][0] |       \
                ma[rr + 2][0];                                                    \
        u64 o = ma[rr - 2][1] | ma[rr - 1][1] | ma[rr][1] | ma[rr + 1][1] |       \
                ma[rr + 2][1];                                                    \
        sp[rr][0] = e | (e << 1) | (e >> 1) | o | (o << 1);                       \
        sp[rr][1] = o | (o << 1) | (o >> 1) | e | (e >> 1);                       \
    }

__global__ __launch_bounds__(512) void k_nms(const float* __restrict__ scores,
                                             u64* __restrict__ surv,
                                             u32* __restrict__ cnt) {
    __shared__ float hb[32][128];                  // 16 KB
    __shared__ __align__(16) u64 ma[128][2];       // [E,O] interleaved
    __shared__ __align__(16) u64 sp[128][2];
    __shared__ u64 skey[SKCAP];                    // 16 KB (separate; hb live)
    __shared__ u32 lcnt, gbase;
    const int b = blockIdx.z;
    const int gx0 = blockIdx.x * TILE_X - 10;
    const int gy0 = blockIdx.y * TILE_Y - 10;
    const float* img = scores + (size_t)b * H * W;
    const int tid = (int)threadIdx.x, lane = tid & 63, w = tid >> 6, rbase = w * 16;
    const int gx = gx0 + 2 * lane;
    if (tid == 0) lcnt = 0;

    float svx[16], svy[16], h0r[16], h1r[16];
    u32 sbx = 0, sby = 0;
#pragma unroll
    for (int i = 0; i < 16; ++i) {
        int gy = gy0 + rbase + i;
        float x = -INFINITY, y = -INFINITY;
        if (gy >= 0 && gy < H) {
            const float* row = img + (size_t)gy * W;
            if (gx >= 0 && gx + 1 < W) {
                float2 t = *(const float2*)(row + gx);
                x = t.x; y = t.y;
            } else if (gx >= 0 && gx < W) {
                x = row[gx];
            }
        }
        svx[i] = x; svy[i] = y;
    }

    ROUND_A(0, 127, false)
    __syncthreads();
    ROUND_B(2, 125, false, 1)
    __syncthreads();
    DILATE(4, 123)
    __syncthreads();
    sbx = 0; sby = 0;
    ROUND_A(4, 123, true)
    __syncthreads();
    ROUND_B(6, 121, true, 0)
    __syncthreads();
    DILATE(8, 119)
    __syncthreads();
    sbx = 0; sby = 0;
    ROUND_A(8, 119, true)
    __syncthreads();
    ROUND_B_FINAL()
    __syncthreads();
    u32 nk = lcnt < SKCAP ? lcnt : SKCAP;
    if (tid == 0) gbase = nk ? atomicAdd(&cnt[b], nk) : 0u;
    __syncthreads();
    for (u32 i = tid; i < nk; i += 512)
        surv[(size_t)b * CAP + gbase + i] = skey[i];
}

// ===== per-chunk private histograms; M (u16) layout [img][chunk][bin] =====
__global__ __launch_bounds__(512) void k_hist(const u64* __restrict__ surv,
                                              const u32* __restrict__ cnt,
                                              u16* __restrict__ M) {
    __shared__ u32 h[NBT];
    int img = blockIdx.x / NCH, c = blockIdx.x % NCH;
    int tid = (int)threadIdx.x;
    for (int i = tid; i < NBT; i += 512) h[i] = 0;
    __syncthreads();
    u32 n = cnt[img];
    if (n > CAP) n = CAP;
    u32 chunk = (n + NCH - 1) / NCH;
    u32 lo = c * chunk, hi = min(n, lo + chunk);
    const u64* sv = surv + (size_t)img * CAP;
    for (u32 i = lo + tid; i < hi; i += 512) atomicAdd(&h[binOf(sv[i])], 1u);
    __syncthreads();
    u16* dst = M + ((size_t)img * NCH + c) * NBT;
    for (int i = tid; i < NBT; i += 512) dst[i] = (u16)h[i];
}

// ===== scan v4: register accumulate + shuffle scan + cooperative offC fill =====
__global__ __launch_bounds__(1024) void k_scan(const u16* __restrict__ M,
                                               u32* __restrict__ offC,
                                               u32* __restrict__ basetot,
                                               int* __restrict__ tinfo,
                                               u64* __restrict__ gkeys) {
    __shared__ u32 wsum[16];
    __shared__ u32 binbase[NBT];   // 32 KB; base slot per (bin - TT)
    __shared__ u32 sh_ntot;
    __shared__ int sh_T;
    __shared__ u32 sh_r, sh_m;
    int img = blockIdx.x, tid = (int)threadIdx.x;
    const u16* Mi = M + (size_t)img * NCH * NBT;
    const int base = NBT - 8 - tid * 8;
    u32 reg[8] = {0, 0, 0, 0, 0, 0, 0, 0};
    for (int c = 0; c < NCH; ++c) {
        const u16* p = Mi + (size_t)c * NBT + base;
        ushort4 a = *(const ushort4*)(p);
        ushort4 b2 = *(const ushort4*)(p + 4);
        reg[0] += a.x; reg[1] += a.y; reg[2] += a.z; reg[3] += a.w;
        reg[4] += b2.x; reg[5] += b2.y; reg[6] += b2.z; reg[7] += b2.w;
    }
    u32 tot = 0;
#pragma unroll
    for (int j = 0; j < 8; ++j) tot += reg[j];
    u32 x = tot;
    int ln = tid & 63, wv = tid >> 6;
#pragma unroll
    for (int off = 1; off < 64; off <<= 1) {
        u32 v = (u32)__shfl_up((int)x, off);
        if (ln >= off) x += v;
    }
    if (ln == 63) wsum[wv] = x;
    __syncthreads();
    if (tid < 16) {
        u32 wval = wsum[tid];
        u32 wx = wval;
        for (int off = 1; off < 16; off <<= 1) {
            u32 v = (u32)__shfl_up((int)wx, off);
            if (tid >= off) wx += v;
        }
        wsum[tid] = wx - wval;
        if (tid == 15) sh_ntot = wx;
    }
    __syncthreads();
    u32 incl = x + wsum[wv];
    u32 excl = incl - tot;
    u32 ntot = sh_ntot;
    if (ntot > TOPK) {
        if (excl < TOPK && TOPK <= incl) {
            u32 cum = excl;
#pragma unroll
            for (int j = 0; j < 8; ++j) {
                u32 cj = reg[7 - j];
                if (cum + cj >= TOPK) {
                    sh_T = NBT - 1 - tid * 8 - j;
                    sh_r = TOPK - cum;
                    sh_m = cj;
                    break;
                }
                cum += cj;
            }
        }
    } else if (tid == 0) { sh_T = -1; sh_r = 0; sh_m = 0; }
    __syncthreads();
    int T = sh_T;
    int TT = (T < 0) ? 0 : T;
    u32* bti = basetot + (size_t)img * NBT;
    // Phase B: register-only base slots (no global reads)
    {
        u32 cum = excl;
        int hi = NBT - 1 - tid * 8;
#pragma unroll
        for (int j = 0; j < 8; ++j) {
            int bin = hi - j;
            u32 c0 = reg[7 - j];
            if (bin > T) {
                binbase[bin - TT] = cum;
                bti[bin] = (cum << 16) | c0;
            } else if (bin == T && T >= 0) {
                binbase[0] = TOPK;  // candidate region base
            }
            cum += c0;
        }
    }
    u64* gk = gkeys + (size_t)img * GK;
    for (int i = tid; i < TOPK; i += 1024) gk[i] = 0ull;
    __syncthreads();
    // Phase C: wave-per-bin cooperative offC fill (parallel chunk loads + scan)
    {
        int R = NBT - TT;
        u32* offi = offC + (size_t)img * NBT * NCH;
        for (int bi = wv; bi < R; bi += 16) {
            u32 val = 0;
            if (ln < NCH) val = Mi[(size_t)ln * NBT + (TT + bi)];
            u32 sc = val;
#pragma unroll
            for (int off = 1; off < NCH; off <<= 1) {
                u32 vv = (u32)__shfl_up((int)sc, off);
                if (ln >= off) sc += vv;
            }
            u32 exclS = sc - val;
            if (ln < NCH) offi[(size_t)bi * NCH + ln] = binbase[bi] + exclS;
        }
    }
    if (tid == 0) {
        tinfo[3 * img] = T;
        tinfo[3 * img + 1] = (int)sh_r;
        tinfo[3 * img + 2] = (int)sh_m;
    }
}

// ===== scatter: preload only R = NBT-TT compact offsets =====
__global__ __launch_bounds__(512) void k_scatter(const u64* __restrict__ surv,
                                                 const u32* __restrict__ cnt,
                                                 const int* __restrict__ tinfo,
                                                 const u32* __restrict__ offC,
                                                 u64* __restrict__ gkeys) {
    __shared__ u32 loff[NBT];
    int img = blockIdx.x / NCH, c = blockIdx.x % NCH;
    int tid = (int)threadIdx.x;
    int T = tinfo[3 * img];
    int TT = (T < 0) ? 0 : T;
    int R = NBT - TT;
    const u32* src = offC + (size_t)img * NBT * NCH;
    for (int i = tid; i < R; i += 512) loff[i] = src[(size_t)i * NCH + c];
    __syncthreads();
    u32 n = cnt[img];
    if (n > CAP) n = CAP;
    u32 chunk = (n + NCH - 1) / NCH;
    u32 lo = c * chunk, hiX = min(n, lo + chunk);
    const u64* sv = surv + (size_t)img * CAP;
    u64* gk = gkeys + (size_t)img * GK;
    for (u32 i = lo + tid; i < hiX; i += 512) {
        u64 kk = sv[i];
        int bb = binOf(kk);
        if (bb < TT) continue;
        u32 slot = atomicAdd(&loff[bb - TT], 1u);
        if (slot < GK) gk[slot] = kk;
    }
}

// ===== finalize: 17 blocks/image, global reads (L2-hot), no LDS staging =====
__global__ __launch_bounds__(256) void k_fin(const int* __restrict__ tinfo,
                                             const u32* __restrict__ basetot,
                                             const u64* __restrict__ gkeys,
                                             u64* __restrict__ sorted) {
    int img = blockIdx.x / 17;
    int slice = blockIdx.x % 17;
    int tid = (int)threadIdx.x;
    int T = tinfo[3 * img];
    u32 r = (u32)tinfo[3 * img + 1];
    u32 m = (u32)tinfo[3 * img + 2];
    if (m > (u32)(GK - TOPK)) m = (u32)(GK - TOPK);
    const u64* gk = gkeys + (size_t)img * GK;
    const u32* bti = basetot + (size_t)img * NBT;
    u64* dst = sorted + (size_t)img * TOPK;
    if (slice < 16) {
        u32 s = (u32)(slice * 256 + tid);
        u32 upper = TOPK - r;
        if (s < upper) {
            u64 kk = gk[s];
            if (kk == 0ull) {
                dst[s] = 0ull;
            } else {
                int bb = binOf(kk);
                u32 v = bti[bb];
                u32 base = v >> 16, cc = v & 0xFFFFu;
                u32 g = 0;
                for (u32 j = 0; j < cc; ++j) g += (gk[base + j] > kk) ? 1u : 0u;
                dst[base + g] = kk;
            }
        }
    } else {
        for (u32 i = (u32)tid; i < m; i += 256) {
            u64 ki = gk[TOPK + i];
            u32 g = 0;
            for (u32 j = 0; j < m; ++j) g += (gk[TOPK + j] > ki) ? 1u : 0u;
            if (g < r) dst[TOPK - r + g] = ki;
        }
    }
}

// ===== wave-parallel output: 2 keypoints/wave, 1 patch element/lane =====
__global__ __launch_bounds__(256) void k_out(const float* __restrict__ scores,
                                             const u64* __restrict__ sorted,
                                             float* __restrict__ out) {
    int gtid = blockIdx.x * 256 + (int)threadIdx.x;
    int wid = gtid >> 6;
    int l = gtid & 63;
    int half = l >> 5;
    int c = l & 31;
    int kpg = wid * 2 + half;
    int b = kpg >> 12;
    int kp = kpg & (TOPK - 1);
    const float* img = scores + (size_t)b * H * W;
    u64 key = sorted[(size_t)b * TOPK + kp];
    u32 idx = ~(u32)(key & 0xFFFFFFFFull);
    int ky = (int)(idx >> 10) & 1023, kx = (int)(idx & 1023);
    ky = min(max(ky, 2), H - 3);
    kx = min(max(kx, 2), W - 3);
    int row = c / 5, col = c % 5;
    float v = 0.0f;
    if (c < 25) v = img[(ky + row - 2) * W + (kx + col - 2)];
    float mx = (c < 25) ? v : -INFINITY;
#pragma unroll
    for (int mk = 1; mk < 32; mk <<= 1) mx = fmaxf(mx, __shfl_xor(mx, mk));
    float e = (c < 25) ? expf((v - mx) / 0.1f) : 0.0f;
    float dxv = (float)(col - 2), dyv = (float)(row - 2);
    float s0 = e, s1 = e * dxv, s2 = e * dyv;
#pragma unroll
    for (int mk = 1; mk < 32; mk <<= 1) {
        s0 += __shfl_xor(s0, mk);
        s1 += __shfl_xor(s1, mk);
        s2 += __shfl_xor(s2, mk);
    }
    float xr = s1 / s0, yr = s2 / s0;
    float ddx = (dxv - xr) * 0.5f, ddy = (dyv - yr) * 0.5f;
    float d = e * (ddx * ddx + ddy * ddy);
#pragma unroll
    for (int mk = 1; mk < 32; mk <<= 1) d += __shfl_xor(d, mk);
    float disp = d / s0;
    float kpx = ((float)kx + xr) / 1023.0f * 2.0f - 1.0f;
    float kpy = ((float)ky + yr) / 1023.0f * 2.0f - 1.0f;
    float px = (kpx + 1.0f) * 0.5f * 1023.0f;
    float py = (kpy + 1.0f) * 0.5f * 1023.0f;
    float fx = floorf(px), fy = floorf(py);
    float wx = px - fx, wy = py - fy;
    int x0 = (int)fminf(fmaxf(fx, 0.f), 1023.f);
    int x1 = (int)fminf(fmaxf(fx + 1.f, 0.f), 1023.f);
    int y0 = (int)fminf(fmaxf(fy, 0.f), 1023.f);
    int y1 = (int)fminf(fmaxf(fy + 1.f, 0.f), 1023.f);
    float bv = 0.0f;
    if (c < 4) {
        int xx = (c & 1) ? x1 : x0;
        int yy = (c >> 1) ? y1 : y0;
        bv = img[yy * W + xx];
    }
    int base = half * 32;
    float v00 = __shfl(bv, base + 0);
    float v01 = __shfl(bv, base + 1);
    float v10 = __shfl(bv, base + 2);
    float v11 = __shfl(bv, base + 3);
    float sc = v00 * (1.f - wx) * (1.f - wy) + v01 * wx * (1.f - wy) +
               v10 * (1.f - wx) * wy + v11 * wx * wy;
    if (c == 0) {
        size_t kb = (size_t)b * TOPK + kp;
        out[kb * 2 + 0] = kpx;
        out[kb * 2 + 1] = kpy;
        out[(size_t)B * TOPK * 2 + kb] = disp;
        out[(size_t)B * TOPK * 3 + kb] = sc;
    }
}

extern "C" void kernel_launch(void* const* d_in, const int* in_sizes, int n_in,
                              void* d_out, int out_size, void* d_ws, size_t ws_size,
                              hipStream_t stream) {
    const float* scores = (const float*)d_in[0];
    float* out = (float*)d_out;
    char* ws = (char*)d_ws;
    u64* surv = (u64*)ws;                                   // 8 MB
    u16* M = (u16*)(ws + 8388608);                          // 2 MB (u16, NCH=16)
    u32* offC = (u32*)(ws + 10485760);                      // 4 MB (compact-indexed)
    u32* basetot = (u32*)(ws + 14680064);                   // 256 KB
    u64* gkeys = (u64*)(ws + 15204352);                     // 1.31 MB
    u64* sorted = (u64*)(ws + 16515072);                    // 256 KB
    u32* cnt = (u32*)(ws + 16777216);                       // 32 B
    int* tinfo = (int*)(ws + 16777280);                     // 96 B

    hipMemsetAsync(cnt, 0, B * sizeof(u32), stream);

    k_nms<<<dim3(GDX, GDY, B), 512, 0, stream>>>(scores, surv, cnt);
    k_hist<<<B * NCH, 512, 0, stream>>>(surv, cnt, M);
    k_scan<<<B, 1024, 0, stream>>>(M, offC, basetot, tinfo, gkeys);
    k_scatter<<<B * NCH, 512, 0, stream>>>(surv, cnt, tinfo, offC, gkeys);
    k_fin<<<B * 17, 256, 0, stream>>>(tinfo, basetot, gkeys, sorted);
    k_out<<<(B * TOPK * 32) / 256, 256, 0, stream>>>(scores, sorted, out);
}

// Round 28
// 97.453 us; speedup vs baseline: 1.2171x; 1.0473x over previous
//
#include <hip/hip_runtime.h>
#include <math.h>

#define H 1024
#define W 1024
#define B 8
#define TOPK 4096
#define NBT 8192
#define NCH 20
#define NBLK 100
#define SPC (NBLK / NCH)
#define SKCAP 2048
#define SPI ((size_t)NBLK * SKCAP)
#define GK 20480
#define TILE_X 108
#define TILE_Y 108
#define GDX 10
#define GDY 10

typedef unsigned long long u64;
typedef unsigned int u32;
typedef unsigned short u16;

// DPP lane shifts (VALU, no DS). wave_shr1 (0x138) == shfl_up(v,1);
// wave_shl1 (0x130) == shfl_down(v,1). bound_ctrl zero-fill at lanes 0/63 is
// harmless: those lanes own region cols {0,1}/{126,127}, excluded by extents.
__device__ __forceinline__ float dpp_up1(float v) {
    int r = __builtin_amdgcn_update_dpp(0, __float_as_int(v), 0x138, 0xF, 0xF, true);
    return __int_as_float(r);
}
__device__ __forceinline__ float dpp_dn1(float v) {
    int r = __builtin_amdgcn_update_dpp(0, __float_as_int(v), 0x130, 0xF, 0xF, true);
    return __int_as_float(r);
}

// Monotone bin index, fine-grained where survivor values cluster (v in [0.5,1)).
__device__ __forceinline__ int binOf(u64 key) {
    u32 fb = (u32)(key >> 32);
    u32 ex = fb >> 23;
    if (ex >= 0x7Fu) return NBT - 1;
    if (ex == 0x7Eu) {
        u32 m13 = (fb >> 10) & 0x1FFFu;
        return (m13 < 64u) ? 64 : (int)m13;
    }
    if (ex >= 0x6Eu) return (int)(ex - 0x6Eu + 47u);
    return 1;
}

// ================= Fused 3-round NMS + survivor compaction =================
#define ROUND_A(VR0, VR1, USE_SUPP)                                               \
    _Pragma("unroll") for (int i = 0; i < 16; ++i) {                              \
        int r = rbase + i;                                                        \
        if (r < (VR0) || r > (VR1)) continue;                                     \
        float x = svx[i], y = svy[i];                                             \
        if (USE_SUPP) {                                                           \
            u64 se = sp[r][0], so = sp[r][1];                                     \
            u32 s0 = (u32)(se >> lane) & 1u;                                      \
            u32 s1 = (u32)(so >> lane) & 1u;                                      \
            sbx |= s0 << i;                                                       \
            sby |= s1 << i;                                                       \
            if (s0) x = 0.0f;                                                     \
            if (s1) y = 0.0f;                                                     \
        }                                                                         \
        float ux = dpp_up1(x), uy = dpp_up1(y);                                   \
        float dxx = dpp_dn1(x), dyy = dpp_dn1(y);                                 \
        float m01 = fmaxf(x, y);                                                  \
        float h0 = fmaxf(fmaxf(ux, uy), fmaxf(m01, dxx));                         \
        float h1 = fmaxf(fmaxf(uy, m01), fmaxf(dxx, dyy));                        \
        h0r[i] = h0;                                                              \
        h1r[i] = h1;                                                              \
        if (i == 0 || i == 1 || i == 14 || i == 15) {                             \
            int k = (i < 2) ? i : i - 12;                                         \
            *(float2*)&hb[w * 4 + k][2 * lane] = make_float2(h0, h1);             \
        }                                                                         \
    }

#define GATHER_V()                                                                \
        float v0x, v0y, v1x, v1y, v3x, v3y, v4x, v4y;                             \
        if (i >= 2) { v0x = h0r[i - 2]; v0y = h1r[i - 2]; }                       \
        else { int k = (i == 0) ? 2 : 3;                                          \
               float2 t = *(const float2*)&hb[(w - 1) * 4 + k][2 * lane];         \
               v0x = t.x; v0y = t.y; }                                            \
        if (i >= 1) { v1x = h0r[i - 1]; v1y = h1r[i - 1]; }                       \
        else { float2 t = *(const float2*)&hb[(w - 1) * 4 + 3][2 * lane];         \
               v1x = t.x; v1y = t.y; }                                            \
        if (i <= 14) { v3x = h0r[i + 1]; v3y = h1r[i + 1]; }                      \
        else { float2 t = *(const float2*)&hb[(w + 1) * 4 + 0][2 * lane];         \
               v3x = t.x; v3y = t.y; }                                            \
        if (i <= 13) { v4x = h0r[i + 2]; v4y = h1r[i + 2]; }                      \
        else { int k = (i == 14) ? 0 : 1;                                         \
               float2 t = *(const float2*)&hb[(w + 1) * 4 + k][2 * lane];         \
               v4x = t.x; v4y = t.y; }

#define ROUND_B(VV0, VV1, USE_SUPP, FIRST)                                        \
    _Pragma("unroll") for (int i = 0; i < 16; ++i) {                              \
        int r = rbase + i;                                                        \
        if (r < (VV0) || r > (VV1)) continue;                                     \
        GATHER_V()                                                                \
        float vm0 = fmaxf(fmaxf(fmaxf(v0x, v1x), fmaxf(v3x, v4x)), h0r[i]);       \
        float vm1 = fmaxf(fmaxf(fmaxf(v0y, v1y), fmaxf(v3y, v4y)), h1r[i]);       \
        float x = svx[i], y = svy[i];                                             \
        bool sb0 = false, sb1 = false;                                            \
        if (USE_SUPP) {                                                           \
            sb0 = (sbx >> i) & 1u;                                                \
            sb1 = (sby >> i) & 1u;                                                \
            if (sb0) x = 0.0f;                                                    \
            if (sb1) y = 0.0f;                                                    \
        }                                                                         \
        int c0 = 2 * lane;                                                        \
        bool bit0 = (x == vm0) && !sb0 && (svx[i] != -INFINITY) &&                \
                    c0 >= (VV0) && c0 <= (VV1);                                   \
        bool bit1 = (y == vm1) && !sb1 && (svy[i] != -INFINITY) &&                \
                    (c0 + 1) >= (VV0) && (c0 + 1) <= (VV1);                       \
        u64 bE = __ballot(bit0), bO = __ballot(bit1);                             \
        if (lane == 0) {                                                          \
            u64 ne = ((FIRST) ? 0ull : ma[r][0]) | bE;                            \
            u64 no = ((FIRST) ? 0ull : ma[r][1]) | bO;                            \
            ma[r][0] = ne;                                                        \
            ma[r][1] = no;                                                        \
        }                                                                         \
    }

#define ROUND_B_FINAL()                                                           \
    _Pragma("unroll") for (int i = 0; i < 16; ++i) {                              \
        int r = rbase + i;                                                        \
        if (r < 10 || r > 117) continue;                                          \
        GATHER_V()                                                                \
        float vm0 = fmaxf(fmaxf(fmaxf(v0x, v1x), fmaxf(v3x, v4x)), h0r[i]);       \
        float vm1 = fmaxf(fmaxf(fmaxf(v0y, v1y), fmaxf(v3y, v4y)), h1r[i]);       \
        float x = svx[i], y = svy[i];                                             \
        bool sb0 = (sbx >> i) & 1u;                                               \
        bool sb1 = (sby >> i) & 1u;                                               \
        if (sb0) x = 0.0f;                                                        \
        if (sb1) y = 0.0f;                                                        \
        int c0 = 2 * lane;                                                        \
        bool bit0 = (x == vm0) && !sb0 && (svx[i] != -INFINITY);                  \
        bool bit1 = (y == vm1) && !sb1 && (svy[i] != -INFINITY);                  \
        u64 me_old = ma[r][0], mo_old = ma[r][1];                                 \
        bool fin0 = bit0 || (((me_old >> lane) & 1ull) != 0);                     \
        bool fin1 = bit1 || (((mo_old >> lane) & 1ull) != 0);                     \
        int gy = gy0 + r;                                                         \
        if (c0 >= 10 && c0 <= 117 && fin0 && svx[i] > 0.0f &&                     \
            gx >= 2 && gx < W - 2 && gy >= 2 && gy < H - 2) {                     \
            u32 pos = atomicAdd(&lcnt, 1u);                                       \
            if (pos < SKCAP) {                                                    \
                u32 p = (u32)(gy * W + gx);                                       \
                skey[pos] = ((u64)__float_as_uint(svx[i]) << 32) | (u64)(~p);     \
            }                                                                     \
        }                                                                         \
        if (c0 + 1 >= 10 && c0 + 1 <= 117 && fin1 && svy[i] > 0.0f &&             \
            gx + 1 >= 2 && gx + 1 < W - 2 && gy >= 2 && gy < H - 2) {             \
            u32 pos = atomicAdd(&lcnt, 1u);                                       \
            if (pos < SKCAP) {                                                    \
                u32 p = (u32)(gy * W + gx + 1);                                   \
                skey[pos] = ((u64)__float_as_uint(svy[i]) << 32) | (u64)(~p);     \
            }                                                                     \
        }                                                                         \
    }

#define DILATE(R0, R1)                                                            \
    if (tid >= (R0) && tid <= (R1)) {                                             \
        int rr = tid;                                                             \
        u64 e = ma[rr - 2][0] | ma[rr - 1][0] | ma[rr][0] | ma[rr + 1][0] |       \
                ma[rr + 2][0];                                                    \
        u64 o = ma[rr - 2][1] | ma[rr - 1][1] | ma[rr][1] | ma[rr + 1][1] |       \
                ma[rr + 2][1];                                                    \
        sp[rr][0] = e | (e << 1) | (e >> 1) | o | (o << 1);                       \
        sp[rr][1] = o | (o << 1) | (o >> 1) | e | (e >> 1);                       \
    }

__global__ __launch_bounds__(512) void k_nms(const float* __restrict__ scores,
                                             u64* __restrict__ surv,
                                             u32* __restrict__ bcnt) {
    __shared__ float hb[32][128];                  // 16 KB
    __shared__ __align__(16) u64 ma[128][2];       // [E,O] interleaved
    __shared__ __align__(16) u64 sp[128][2];
    __shared__ u64 skey[SKCAP];                    // 16 KB (separate; hb live)
    __shared__ u32 lcnt;
    const int b = blockIdx.z;
    const int slot = blockIdx.y * GDX + blockIdx.x;
    const int gx0 = blockIdx.x * TILE_X - 10;
    const int gy0 = blockIdx.y * TILE_Y - 10;
    const float* img = scores + (size_t)b * H * W;
    const int tid = (int)threadIdx.x, lane = tid & 63, w = tid >> 6, rbase = w * 16;
    const int gx = gx0 + 2 * lane;
    if (tid == 0) lcnt = 0;

    float svx[16], svy[16], h0r[16], h1r[16];
    u32 sbx = 0, sby = 0;
#pragma unroll
    for (int i = 0; i < 16; ++i) {
        int gy = gy0 + rbase + i;
        float x = -INFINITY, y = -INFINITY;
        if (gy >= 0 && gy < H) {
            const float* row = img + (size_t)gy * W;
            if (gx >= 0 && gx + 1 < W) {
                float2 t = *(const float2*)(row + gx);
                x = t.x; y = t.y;
            } else if (gx >= 0 && gx < W) {
                x = row[gx];
            }
        }
        svx[i] = x; svy[i] = y;
    }

    ROUND_A(0, 127, false)
    __syncthreads();
    ROUND_B(2, 125, false, 1)
    __syncthreads();
    DILATE(4, 123)
    __syncthreads();
    sbx = 0; sby = 0;
    ROUND_A(4, 123, true)
    __syncthreads();
    ROUND_B(6, 121, true, 0)
    __syncthreads();
    DILATE(8, 119)
    __syncthreads();
    sbx = 0; sby = 0;
    ROUND_A(8, 119, true)
    __syncthreads();
    ROUND_B_FINAL()
    __syncthreads();
    u32 nk = lcnt < SKCAP ? lcnt : SKCAP;
    u64* dst = surv + (size_t)b * SPI + (size_t)slot * SKCAP;
    for (u32 i = tid; i < nk; i += 512) dst[i] = skey[i];
    if (tid == 0) bcnt[b * NBLK + slot] = nk;
}

// ===== per-chunk private histograms; chunk = SPC block-slots =====
__global__ __launch_bounds__(512) void k_hist(const u64* __restrict__ surv,
                                              const u32* __restrict__ bcnt,
                                              u16* __restrict__ M) {
    __shared__ u32 h[NBT];
    int img = blockIdx.x / NCH, c = blockIdx.x % NCH;
    int tid = (int)threadIdx.x;
    for (int i = tid; i < NBT; i += 512) h[i] = 0;
    __syncthreads();
    for (int s = c * SPC; s < (c + 1) * SPC; ++s) {
        u32 nk = bcnt[img * NBLK + s];
        if (nk > SKCAP) nk = SKCAP;
        const u64* sv = surv + (size_t)img * SPI + (size_t)s * SKCAP;
        for (u32 i = tid; i < nk; i += 512) atomicAdd(&h[binOf(sv[i])], 1u);
    }
    __syncthreads();
    u16* dst = M + ((size_t)img * NCH + c) * NBT;
    for (int i = tid; i < NBT; i += 512) dst[i] = (u16)h[i];
}

// ===== scan: register accumulate + shuffle scan + cooperative offC fill =====
__global__ __launch_bounds__(1024) void k_scan(const u16* __restrict__ M,
                                               u32* __restrict__ offC,
                                               u32* __restrict__ basetot,
                                               int* __restrict__ tinfo,
                                               u64* __restrict__ gkeys) {
    __shared__ u32 wsum[16];
    __shared__ u32 binbase[NBT];
    __shared__ u32 sh_ntot;
    __shared__ int sh_T;
    __shared__ u32 sh_r, sh_m;
    int img = blockIdx.x, tid = (int)threadIdx.x;
    const u16* Mi = M + (size_t)img * NCH * NBT;
    const int base = NBT - 8 - tid * 8;
    u32 reg[8] = {0, 0, 0, 0, 0, 0, 0, 0};
    for (int c = 0; c < NCH; ++c) {
        const u16* p = Mi + (size_t)c * NBT + base;
        ushort4 a = *(const ushort4*)(p);
        ushort4 b2 = *(const ushort4*)(p + 4);
        reg[0] += a.x; reg[1] += a.y; reg[2] += a.z; reg[3] += a.w;
        reg[4] += b2.x; reg[5] += b2.y; reg[6] += b2.z; reg[7] += b2.w;
    }
    u32 tot = 0;
#pragma unroll
    for (int j = 0; j < 8; ++j) tot += reg[j];
    u32 x = tot;
    int ln = tid & 63, wv = tid >> 6;
#pragma unroll
    for (int off = 1; off < 64; off <<= 1) {
        u32 v = (u32)__shfl_up((int)x, off);
        if (ln >= off) x += v;
    }
    if (ln == 63) wsum[wv] = x;
    __syncthreads();
    if (tid < 16) {
        u32 wval = wsum[tid];
        u32 wx = wval;
        for (int off = 1; off < 16; off <<= 1) {
            u32 v = (u32)__shfl_up((int)wx, off);
            if (tid >= off) wx += v;
        }
        wsum[tid] = wx - wval;
        if (tid == 15) sh_ntot = wx;
    }
    __syncthreads();
    u32 incl = x + wsum[wv];
    u32 excl = incl - tot;
    u32 ntot = sh_ntot;
    if (ntot > TOPK) {
        if (excl < TOPK && TOPK <= incl) {
            u32 cum = excl;
#pragma unroll
            for (int j = 0; j < 8; ++j) {
                u32 cj = reg[7 - j];
                if (cum + cj >= TOPK) {
                    sh_T = NBT - 1 - tid * 8 - j;
                    sh_r = TOPK - cum;
                    sh_m = cj;
                    break;
                }
                cum += cj;
            }
        }
    } else if (tid == 0) { sh_T = -1; sh_r = 0; sh_m = 0; }
    __syncthreads();
    int T = sh_T;
    int TT = (T < 0) ? 0 : T;
    u32* bti = basetot + (size_t)img * NBT;
    {
        u32 cum = excl;
        int hi = NBT - 1 - tid * 8;
#pragma unroll
        for (int j = 0; j < 8; ++j) {
            int bin = hi - j;
            u32 c0 = reg[7 - j];
            if (bin > T) {
                binbase[bin - TT] = cum;
                bti[bin] = (cum << 16) | c0;
            } else if (bin == T && T >= 0) {
                binbase[0] = TOPK;
            }
            cum += c0;
        }
    }
    u64* gk = gkeys + (size_t)img * GK;
    for (int i = tid; i < TOPK; i += 1024) gk[i] = 0ull;
    __syncthreads();
    {
        int R = NBT - TT;
        u32* offi = offC + (size_t)img * NBT * NCH;
        for (int bi = wv; bi < R; bi += 16) {
            u32 val = 0;
            if (ln < NCH) val = Mi[(size_t)ln * NBT + (TT + bi)];
            u32 sc = val;
#pragma unroll
            for (int off = 1; off < 32; off <<= 1) {
                u32 vv = (u32)__shfl_up((int)sc, off);
                if (ln >= off) sc += vv;
            }
            u32 exclS = sc - val;
            if (ln < NCH) offi[(size_t)bi * NCH + ln] = binbase[bi] + exclS;
        }
    }
    if (tid == 0) {
        tinfo[3 * img] = T;
        tinfo[3 * img + 1] = (int)sh_r;
        tinfo[3 * img + 2] = (int)sh_m;
    }
}

// ===== scatter: chunk = SPC block-slots; preload compact offsets =====
__global__ __launch_bounds__(512) void k_scatter(const u64* __restrict__ surv,
                                                 const u32* __restrict__ bcnt,
                                                 const int* __restrict__ tinfo,
                                                 const u32* __restrict__ offC,
                                                 u64* __restrict__ gkeys) {
    __shared__ u32 loff[NBT];
    int img = blockIdx.x / NCH, c = blockIdx.x % NCH;
    int tid = (int)threadIdx.x;
    int T = tinfo[3 * img];
    int TT = (T < 0) ? 0 : T;
    int R = NBT - TT;
    const u32* src = offC + (size_t)img * NBT * NCH;
    for (int i = tid; i < R; i += 512) loff[i] = src[(size_t)i * NCH + c];
    __syncthreads();
    u64* gk = gkeys + (size_t)img * GK;
    for (int s = c * SPC; s < (c + 1) * SPC; ++s) {
        u32 nk = bcnt[img * NBLK + s];
        if (nk > SKCAP) nk = SKCAP;
        const u64* sv = surv + (size_t)img * SPI + (size_t)s * SKCAP;
        for (u32 i = tid; i < nk; i += 512) {
            u64 kk = sv[i];
            int bb = binOf(kk);
            if (bb < TT) continue;
            u32 slot = atomicAdd(&loff[bb - TT], 1u);
            if (slot < GK) gk[slot] = kk;
        }
    }
}

// ===== finalize: 17 blocks/image, global reads (L2-hot), no LDS staging =====
__global__ __launch_bounds__(256) void k_fin(const int* __restrict__ tinfo,
                                             const u32* __restrict__ basetot,
                                             const u64* __restrict__ gkeys,
                                             u64* __restrict__ sorted) {
    int img = blockIdx.x / 17;
    int slice = blockIdx.x % 17;
    int tid = (int)threadIdx.x;
    int T = tinfo[3 * img];
    u32 r = (u32)tinfo[3 * img + 1];
    u32 m = (u32)tinfo[3 * img + 2];
    if (m > (u32)(GK - TOPK)) m = (u32)(GK - TOPK);
    const u64* gk = gkeys + (size_t)img * GK;
    const u32* bti = basetot + (size_t)img * NBT;
    u64* dst = sorted + (size_t)img * TOPK;
    if (slice < 16) {
        u32 s = (u32)(slice * 256 + tid);
        u32 upper = TOPK - r;
        if (s < upper) {
            u64 kk = gk[s];
            if (kk == 0ull) {
                dst[s] = 0ull;
            } else {
                int bb = binOf(kk);
                u32 v = bti[bb];
                u32 base = v >> 16, cc = v & 0xFFFFu;
                u32 g = 0;
                for (u32 j = 0; j < cc; ++j) g += (gk[base + j] > kk) ? 1u : 0u;
                dst[base + g] = kk;
            }
        }
    } else {
        for (u32 i = (u32)tid; i < m; i += 256) {
            u64 ki = gk[TOPK + i];
            u32 g = 0;
            for (u32 j = 0; j < m; ++j) g += (gk[TOPK + j] > ki) ? 1u : 0u;
            if (g < r) dst[TOPK - r + g] = ki;
        }
    }
}

// ===== wave-parallel output: 2 keypoints/wave, 1 patch element/lane =====
__global__ __launch_bounds__(256) void k_out(const float* __restrict__ scores,
                                             const u64* __restrict__ sorted,
                                             float* __restrict__ out) {
    int gtid = blockIdx.x * 256 + (int)threadIdx.x;
    int wid = gtid >> 6;
    int l = gtid & 63;
    int half = l >> 5;
    int c = l & 31;
    int kpg = wid * 2 + half;
    int b = kpg >> 12;
    int kp = kpg & (TOPK - 1);
    const float* img = scores + (size_t)b * H * W;
    u64 key = sorted[(size_t)b * TOPK + kp];
    u32 idx = ~(u32)(key & 0xFFFFFFFFull);
    int ky = (int)(idx >> 10) & 1023, kx = (int)(idx & 1023);
    ky = min(max(ky, 2), H - 3);
    kx = min(max(kx, 2), W - 3);
    int row = c / 5, col = c % 5;
    float v = 0.0f;
    if (c < 25) v = img[(ky + row - 2) * W + (kx + col - 2)];
    float mx = (c < 25) ? v : -INFINITY;
#pragma unroll
    for (int mk = 1; mk < 32; mk <<= 1) mx = fmaxf(mx, __shfl_xor(mx, mk));
    float e = (c < 25) ? expf((v - mx) / 0.1f) : 0.0f;
    float dxv = (float)(col - 2), dyv = (float)(row - 2);
    float s0 = e, s1 = e * dxv, s2 = e * dyv;
#pragma unroll
    for (int mk = 1; mk < 32; mk <<= 1) {
        s0 += __shfl_xor(s0, mk);
        s1 += __shfl_xor(s1, mk);
        s2 += __shfl_xor(s2, mk);
    }
    float xr = s1 / s0, yr = s2 / s0;
    float ddx = (dxv - xr) * 0.5f, ddy = (dyv - yr) * 0.5f;
    float d = e * (ddx * ddx + ddy * ddy);
#pragma unroll
    for (int mk = 1; mk < 32; mk <<= 1) d += __shfl_xor(d, mk);
    float disp = d / s0;
    float kpx = ((float)kx + xr) / 1023.0f * 2.0f - 1.0f;
    float kpy = ((float)ky + yr) / 1023.0f * 2.0f - 1.0f;
    float px = (kpx + 1.0f) * 0.5f * 1023.0f;
    float py = (kpy + 1.0f) * 0.5f * 1023.0f;
    float fx = floorf(px), fy = floorf(py);
    float wx = px - fx, wy = py - fy;
    int x0 = (int)fminf(fmaxf(fx, 0.f), 1023.f);
    int x1 = (int)fminf(fmaxf(fx + 1.f, 0.f), 1023.f);
    int y0 = (int)fminf(fmaxf(fy, 0.f), 1023.f);
    int y1 = (int)fminf(fmaxf(fy + 1.f, 0.f), 1023.f);
    float bv = 0.0f;
    if (c < 4) {
        int xx = (c & 1) ? x1 : x0;
        int yy = (c >> 1) ? y1 : y0;
        bv = img[yy * W + xx];
    }
    int base = half * 32;
    float v00 = __shfl(bv, base + 0);
    float v01 = __shfl(bv, base + 1);
    float v10 = __shfl(bv, base + 2);
    float v11 = __shfl(bv, base + 3);
    float sc = v00 * (1.f - wx) * (1.f - wy) + v01 * wx * (1.f - wy) +
               v10 * (1.f - wx) * wy + v11 * wx * wy;
    if (c == 0) {
        size_t kb = (size_t)b * TOPK + kp;
        out[kb * 2 + 0] = kpx;
        out[kb * 2 + 1] = kpy;
        out[(size_t)B * TOPK * 2 + kb] = disp;
        out[(size_t)B * TOPK * 3 + kb] = sc;
    }
}

extern "C" void kernel_launch(void* const* d_in, const int* in_sizes, int n_in,
                              void* d_out, int out_size, void* d_ws, size_t ws_size,
                              hipStream_t stream) {
    const float* scores = (const float*)d_in[0];
    float* out = (float*)d_out;
    char* ws = (char*)d_ws;
    u64* surv = (u64*)ws;                                   // 13.11 MB (slotted)
    u16* M = (u16*)(ws + 13107200);                         // 2.62 MB
    u32* offC = (u32*)(ws + 15728640);                      // 5.24 MB
    u32* basetot = (u32*)(ws + 20971520);                   // 256 KB
    u64* gkeys = (u64*)(ws + 21233664);                     // 1.31 MB
    u64* sorted = (u64*)(ws + 22544384);                    // 256 KB
    u32* bcnt = (u32*)(ws + 22806528);                      // 3.2 KB
    int* tinfo = (int*)(ws + 22810624);                     // 96 B

    k_nms<<<dim3(GDX, GDY, B), 512, 0, stream>>>(scores, surv, bcnt);
    k_hist<<<B * NCH, 512, 0, stream>>>(surv, bcnt, M);
    k_scan<<<B, 1024, 0, stream>>>(M, offC, basetot, tinfo, gkeys);
    k_scatter<<<B * NCH, 512, 0, stream>>>(surv, bcnt, tinfo, offC, gkeys);
    k_fin<<<B * 17, 256, 0, stream>>>(tinfo, basetot, gkeys, sorted);
    k_out<<<(B * TOPK * 32) / 256, 256, 0, stream>>>(scores, sorted, out);
}